// Round 17
// baseline (846.644 us; speedup 1.0000x reference)
//
#include <hip/hip_runtime.h>

#define EPS_BN 1e-5f
#define ROWPAD 8    // CSR rows padded to multiple of 8 edges (src=0,w=0 filler)
#define HSEG 32768  // histogram bins per segment (packed u8 -> 32 KB LDS)
#define HC 64       // histogram edge-chunks
#define MAXB 512    // max dst-buckets (256 nodes each)
#define PM 24       // pooling chunks per graph (64*24=1536 blocks, ~6/CU)
#define PWB 2048    // prop64b grid-stride blocks (8192 waves, ~12 nodes/wave)

typedef unsigned short u16;
typedef unsigned char u8;
typedef int v4i __attribute__((ext_vector_type(4)));
typedef short bf8v __attribute__((ext_vector_type(8)));   // 8 bf16 (4 VGPRs) MFMA A/B frag
typedef float f4v __attribute__((ext_vector_type(4)));    // MFMA C/D frag

__device__ __forceinline__ float b2f(u16 u) {
  return __uint_as_float(((unsigned)u) << 16);
}
__device__ __forceinline__ u16 f2b(float f) {  // RTNE
  unsigned u = __float_as_uint(f);
  u += 0x7fffu + ((u >> 16) & 1u);
  return (u16)(u >> 16);
}

// ---------------- preprocessing: packed-u8 LDS segmented histograms ----------------
// int4 vectorized edge loads (latency-bound fix): 8 edges in flight per thread.
__global__ void k_histseg(const int* __restrict__ src, const int* __restrict__ dst,
                          unsigned* __restrict__ partial, int E, int SP) {
  __shared__ unsigned bins[HSEG / 4];
  int s = blockIdx.x, c = blockIdx.y, z = blockIdx.z;
  int t = threadIdx.x;
  for (int i = t; i < HSEG / 4; i += 256) bins[i] = 0;
  __syncthreads();
  const int* keys = z ? dst : src;
  int lo = s * HSEG;

#define UPD(kk) { int k = (kk) - lo; \
    if ((unsigned)k < (unsigned)HSEG) atomicAdd(&bins[k >> 2], 1u << ((k & 3) * 8)); }

  if ((E & 3) == 0) {  // int4 path (dst = ei+E stays 16B-aligned)
    int E4 = E >> 2;
    int ck = (E4 + HC - 1) / HC;
    int i0 = c * ck, i1 = i0 + ck; if (i1 > E4) i1 = E4;
    const int4* k4 = (const int4*)keys;
    int i = i0 + t;
    for (; i + 256 < i1; i += 512) {
      int4 a = k4[i];
      int4 b = k4[i + 256];
      UPD(a.x); UPD(a.y); UPD(a.z); UPD(a.w);
      UPD(b.x); UPD(b.y); UPD(b.z); UPD(b.w);
    }
    if (i < i1) {
      int4 a = k4[i];
      UPD(a.x); UPD(a.y); UPD(a.z); UPD(a.w);
    }
  } else {  // scalar fallback
    int ck = (E + HC - 1) / HC;
    int e0 = c * ck, e1 = e0 + ck; if (e1 > E) e1 = E;
    for (int e = e0 + t; e < e1; e += 256) UPD(keys[e]);
  }
#undef UPD
  __syncthreads();
  unsigned* out = partial + (size_t)(z * HC + c) * (SP >> 2) + (lo >> 2);
  for (int i = t; i < HSEG / 4; i += 256) out[i] = bins[i];
}

__global__ void k_histred(const u8* __restrict__ partial, float* __restrict__ dinv,
                          int* __restrict__ hist, int N, int SP) {
  int n = blockIdx.x * 256 + threadIdx.x;
  if (n >= N) return;
  int a = 0, b = 0;
  for (int c = 0; c < HC; c++) a += partial[(size_t)c * SP + n];
  for (int c = 0; c < HC; c++) b += partial[(size_t)(HC + c) * SP + n];
  dinv[n] = a > 0 ? rsqrtf((float)a) : 0.f;
  hist[n] = b;
}

// ---- hierarchical scan over PADDED counts ----
#define SC_CHUNK 400

__device__ __forceinline__ int lds_incl_scan256(int* lds, int t, int v) {
  lds[t] = v; __syncthreads();
  for (int off = 1; off < 256; off <<= 1) {
    int u = (t >= off) ? lds[t - off] : 0;
    __syncthreads();
    lds[t] += u;
    __syncthreads();
  }
  return lds[t];
}

__device__ __forceinline__ int padcnt(int h) { return (h + (ROWPAD - 1)) & ~(ROWPAD - 1); }

__global__ void k_scan1(const int* __restrict__ hist, int* __restrict__ bsum, int N) {
  __shared__ int lds[256];
  int b = blockIdx.x, t = threadIdx.x;
  int lo = b * SC_CHUNK;
  int hi = lo + SC_CHUNK; if (hi > N) hi = N;
  int i0 = lo + t * 2;
  int s = 0;
  if (i0 < hi) s += padcnt(hist[i0]);
  if (i0 + 1 < hi) s += padcnt(hist[i0 + 1]);
  int incl = lds_incl_scan256(lds, t, s);
  if (t == 255) bsum[b] = incl;
}

__global__ void k_scan2(const int* __restrict__ bsum, int* __restrict__ bbase, int nb) {
  __shared__ int lds[256];
  int t = threadIdx.x;
  int v = (t < nb) ? bsum[t] : 0;
  int incl = lds_incl_scan256(lds, t, v);
  if (t < nb) bbase[t] = incl - v;
  if (t == nb - 1) bbase[nb] = incl;
}

__global__ void k_scan3(const int* __restrict__ hist, const int* __restrict__ bbase,
                        int* __restrict__ offs, int N, int nb) {
  __shared__ int lds[256];
  int b = blockIdx.x, t = threadIdx.x;
  int lo = b * SC_CHUNK;
  int hi = lo + SC_CHUNK; if (hi > N) hi = N;
  int i0 = lo + t * 2;
  int h0 = (i0 < hi) ? padcnt(hist[i0]) : 0;
  int h1 = (i0 + 1 < hi) ? padcnt(hist[i0 + 1]) : 0;
  int s = h0 + h1;
  int incl = lds_incl_scan256(lds, t, s);
  int run = bbase[b] + incl - s;
  if (i0 < hi) offs[i0] = run;
  if (i0 + 1 < hi) offs[i0 + 1] = run + h0;
  if (b == 0 && t == 0) offs[N] = bbase[nb];
}

// ---------------- two-phase binned scatter ----------------
__global__ void k_bcnt(const int* __restrict__ hist, int* __restrict__ bcnt, int N) {
  __shared__ int red[256];
  int b = blockIdx.x, t = threadIdx.x;
  int n = (b << 8) + t;
  red[t] = (n < N) ? hist[n] : 0;
  __syncthreads();
  for (int off = 128; off; off >>= 1) {
    if (t < off) red[t] += red[t + off];
    __syncthreads();
  }
  if (t == 0) bcnt[b] = red[0];
}

__global__ void k_bscan(const int* __restrict__ bcnt, int* __restrict__ bbase2,
                        int* __restrict__ bcur, int nb) {
  __shared__ int lds[256];
  int t = threadIdx.x;
  int i0 = 2 * t, i1 = 2 * t + 1;
  int v0 = (i0 < nb) ? bcnt[i0] : 0;
  int v1 = (i1 < nb) ? bcnt[i1] : 0;
  int s = v0 + v1;
  int incl = lds_incl_scan256(lds, t, s);
  int ex = incl - s;
  if (i0 < nb) { bbase2[i0] = ex; bcur[i0] = ex; }
  if (i1 < nb) { bbase2[i1] = ex + v0; bcur[i1] = ex + v0; }
  if (t == 255) bbase2[nb] = incl;
}

__global__ void k_part(const int* __restrict__ src, const int* __restrict__ dst,
                       int* __restrict__ bcur, int2* __restrict__ ebuck, int E) {
  __shared__ int lcnt[MAXB], lbase[MAXB];
  int t = threadIdx.x;
  for (int i = t; i < MAXB; i += 256) lcnt[i] = 0;
  __syncthreads();
  int ck = (E + gridDim.x - 1) / gridDim.x;
  int e0 = blockIdx.x * ck, e1 = e0 + ck; if (e1 > E) e1 = E;
  for (int e = e0 + t; e < e1; e += 256) atomicAdd(&lcnt[dst[e] >> 8], 1);
  __syncthreads();
  for (int i = t; i < MAXB; i += 256) {
    int c = lcnt[i];
    lbase[i] = c ? atomicAdd(&bcur[i], c) : 0;
    lcnt[i] = 0;
  }
  __syncthreads();
  for (int e = e0 + t; e < e1; e += 256) {
    int d = dst[e];
    int b = d >> 8;
    int ofs = atomicAdd(&lcnt[b], 1);
    int2 r; r.x = src[e]; r.y = d;
    ebuck[lbase[b] + ofs] = r;
  }
}

__global__ void k_place(const int2* __restrict__ ebuck, const int* __restrict__ bbase2,
                        const int* __restrict__ offs, const float* __restrict__ dinv,
                        int2* __restrict__ erec, int N) {
  __shared__ int lcur[256];
  int b = blockIdx.x, t = threadIdx.x;
  lcur[t] = 0;
  __syncthreads();
  int nlo = b << 8;
  int e0 = bbase2[b], e1 = bbase2[b + 1];
  for (int e = e0 + t; e < e1; e += 256) {
    int2 sd = ebuck[e];
    int s = sd.x, d = sd.y;
    int ofs = atomicAdd(&lcur[d - nlo], 1);
    int2 r;
    r.x = s;
    r.y = __float_as_int(-dinv[s] * dinv[d]);
    erec[offs[d] + ofs] = r;
  }
  __syncthreads();
  int n = nlo + t;
  if (n < N) {
    int st = offs[n] + lcur[t];
    int en = offs[n + 1];
    int2 z; z.x = 0; z.y = 0;
    for (int p = st; p < en; p++) erec[p] = z;
  }
}

// ---------------- propagation (padded CSR, bf16 features, grid-stride + offs prefetch) ----
// Was: one node per wave, one shot -> 3-hop dependent-load chain (offs -> records ->
// gathers, ~700 cy serial) per wave with only ~50 cy of work; 8 waves/SIMD can't hide it.
// Now: 2048 blocks grid-stride (~12 nodes/wave); next node's offs pair prefetched before
// processing the current node (hides one L2 hop + gives scheduler cross-node ILP);
// loop-invariant gab/oab loads hoisted. Per-node arithmetic order unchanged.
__global__ void k_prop64b(const u16* __restrict__ gf, const float* __restrict__ gab,
                          const u16* __restrict__ oldv, const float* __restrict__ oab,
                          u16* __restrict__ outv, const int* __restrict__ offs,
                          const v4i* __restrict__ erec4, int N, int recur) {
  int gw = (blockIdx.x * 256 + threadIdx.x) >> 6;
  int nw = gridDim.x << 2;  // 4 waves per 256-thread block
  int lane = threadIdx.x & 63;
  if (gw >= N) return;
  // hoisted per-lane scale/shift loads (loop-invariant)
  float ga = 0.f, gb = 0.f, oa = 0.f, ob = 0.f;
  if (gab) { ga = gab[lane]; gb = gab[64 + lane]; }
  if (oab) { oa = oab[lane]; ob = oab[64 + lane]; }
  int row = __builtin_amdgcn_readfirstlane(gw);
  int q = offs[row] >> 1, qe = offs[row + 1] >> 1;
  for (int wid = gw; wid < N; ) {
    // prefetch next node's offs pair (hides one L2 hop under this node's work)
    int nxt = wid + nw;
    int nq = 0, nqe = 0;
    if (nxt < N) {
      int nrow = __builtin_amdgcn_readfirstlane(nxt);
      nq = offs[nrow] >> 1;
      nqe = offs[nrow + 1] >> 1;
    }
    float acc = 0.f, sw = 0.f;
    for (; q + 8 <= qe; q += 8) {  // 16 records
      v4i m[8];
#pragma unroll
      for (int j = 0; j < 8; j++) m[j] = erec4[q + j];
      u16 g[16];
#pragma unroll
      for (int j = 0; j < 8; j++) {
        g[2 * j]     = gf[(size_t)m[j].x * 64 + lane];
        g[2 * j + 1] = gf[(size_t)m[j].z * 64 + lane];
      }
#pragma unroll
      for (int j = 0; j < 8; j++) {
        float w0 = __int_as_float(m[j].y), w1 = __int_as_float(m[j].w);
        acc += w0 * b2f(g[2 * j]) + w1 * b2f(g[2 * j + 1]);
        sw += w0 + w1;
      }
    }
    if (q < qe) {  // exactly 8 records
      v4i m[4];
#pragma unroll
      for (int j = 0; j < 4; j++) m[j] = erec4[q + j];
      u16 g[8];
#pragma unroll
      for (int j = 0; j < 4; j++) {
        g[2 * j]     = gf[(size_t)m[j].x * 64 + lane];
        g[2 * j + 1] = gf[(size_t)m[j].z * 64 + lane];
      }
#pragma unroll
      for (int j = 0; j < 4; j++) {
        float w0 = __int_as_float(m[j].y), w1 = __int_as_float(m[j].w);
        acc += w0 * b2f(g[2 * j]) + w1 * b2f(g[2 * j + 1]);
        sw += w0 + w1;
      }
    }
    float res = acc;
    if (gab) res = ga * acc + gb * sw;
    int idx = wid * 64 + lane;
    if (recur) {
      float o = b2f(oldv[idx]);
      if (oab) o = oa * o + ob;
      res = 2.f * res - o;
    }
    outv[idx] = f2b(res);
    wid = nxt; q = nq; qe = nqe;
  }
}

// F=3 f32 variant (layer 1)
__global__ void k_prop3(const float* __restrict__ gf, const float* __restrict__ oldv,
                        float* __restrict__ outv, const int* __restrict__ offs,
                        const v4i* __restrict__ erec4, int N, int recur) {
  int n = blockIdx.x * 256 + threadIdx.x;
  if (n >= N) return;
  int q = offs[n] >> 1, qe = offs[n + 1] >> 1;
  float a0 = 0.f, a1 = 0.f, a2 = 0.f;
  for (; q < qe; q += 4) {
    v4i m[4];
#pragma unroll
    for (int j = 0; j < 4; j++) m[j] = erec4[q + j];
#pragma unroll
    for (int j = 0; j < 4; j++) {
      float w0 = __int_as_float(m[j].y), w1 = __int_as_float(m[j].w);
      int s0 = m[j].x, s1 = m[j].z;
      a0 += w0 * gf[s0 * 3 + 0] + w1 * gf[s1 * 3 + 0];
      a1 += w0 * gf[s0 * 3 + 1] + w1 * gf[s1 * 3 + 1];
      a2 += w0 * gf[s0 * 3 + 2] + w1 * gf[s1 * 3 + 2];
    }
  }
  if (recur) {
    a0 = 2.f * a0 - oldv[n * 3 + 0];
    a1 = 2.f * a1 - oldv[n * 3 + 1];
    a2 = 2.f * a2 - oldv[n * 3 + 2];
  }
  outv[n * 3 + 0] = a0;
  outv[n * 3 + 1] = a1;
  outv[n * 3 + 2] = a2;
}

// ---------------- weight prep: f32 [4][64][FOUT] -> bf16 [4][FOUT][64] (transposed) ----------------
__global__ void k_wprep(const float* __restrict__ W2, const float* __restrict__ W3,
                        const float* __restrict__ W4, u16* __restrict__ WT2,
                        u16* __restrict__ WT3, u16* __restrict__ WT4) {
  int tid = blockIdx.x * 256 + threadIdx.x;
  if (tid < 16384) {
    int p = tid >> 12, j = (tid >> 6) & 63, k = tid & 63;
    WT2[tid] = f2b(W2[p * 4096 + k * 64 + j]);
    WT3[tid] = f2b(W3[p * 4096 + k * 64 + j]);
  }
  if (tid < 8192) {
    int p = tid >> 11, j = (tid >> 6) & 31, k = tid & 63;
    WT4[tid] = f2b(W4[p * 2048 + k * 32 + j]);
  }
}

// ---------------- MFMA combine: out = bias2 + sum_p Tp @ Wp  (K=256, bf16 MFMA) ----------------
// Weights-stationary: all B-fragments held in registers for the whole kernel
// (FOUT=64: 32 frags = 128 VGPRs). Each block grid-strides over 64-node tiles;
// inner loop = 8 coalesced 16B A-loads + 32 MFMAs, zero LDS traffic.
// BN sum/sumsq accumulate in registers across tiles; one LDS reduce + one
// atomicAdd pair per block at the end.
// A-frag: A[m=lane&15][k=quad*8+j] direct from T tables.
// B-frag: B[k][n=lane&15] from WT (bf16 [4][FOUT][64]); ab folded into p=0.
// C/D: col=lane&15, row=quad*4+reg.
template <int FOUT, bool OUTBF, bool DOBN>
__global__ __launch_bounds__(256, 2) void k_combine_m(
    void* __restrict__ outp, const u16* __restrict__ T0, const u16* __restrict__ T1,
    const u16* __restrict__ T2, const u16* __restrict__ T3, const u16* __restrict__ WTg,
    const float* __restrict__ ab, const float* __restrict__ bias2,
    float* __restrict__ gs, int N, int ntiles) {
  constexpr int NT = FOUT / 16;
  __shared__ float red[2 * FOUT * 16];
  int tid = threadIdx.x;
  int wv = tid >> 6, lane = tid & 63;
  int col = lane & 15, quad = lane >> 4;

  // ---- stage B into registers (weights-stationary), fold a[k] into p==0 ----
  bf8v B[4][2][NT];
#pragma unroll
  for (int p = 0; p < 4; p++) {
#pragma unroll
    for (int kb = 0; kb < 2; kb++) {
      f4v sc0, sc1;
      if (p == 0) {
        sc0 = *(const f4v*)(ab + kb * 32 + quad * 8);
        sc1 = *(const f4v*)(ab + kb * 32 + quad * 8 + 4);
      }
#pragma unroll
      for (int t = 0; t < NT; t++) {
        bf8v b = *(const bf8v*)(WTg + (size_t)(p * FOUT + t * 16 + col) * 64 + kb * 32 + quad * 8);
        if (p == 0) {
#pragma unroll
          for (int i = 0; i < 8; i++) {
            float sc = (i < 4) ? sc0[i] : sc1[i - 4];
            b[i] = (short)f2b(sc * b2f((u16)b[i]));
          }
        }
        B[p][kb][t] = b;
      }
    }
  }

  float bv[NT];
#pragma unroll
  for (int t = 0; t < NT; t++) bv[t] = bias2[t * 16 + col];

  float sum_[NT], sq_[NT];
#pragma unroll
  for (int t = 0; t < NT; t++) { sum_[t] = 0.f; sq_[t] = 0.f; }

  const u16* Tp[4] = {T0, T1, T2, T3};

  for (int tile = blockIdx.x; tile < ntiles; tile += gridDim.x) {
    int nb = tile * 64 + wv * 16;
    int node = nb + col;
    bool valid = node < N;

    bf8v A[4][2];
#pragma unroll
    for (int p = 0; p < 4; p++) {
#pragma unroll
      for (int kb = 0; kb < 2; kb++) {
        if (valid) {
          A[p][kb] = *(const bf8v*)(Tp[p] + (size_t)node * 64 + kb * 32 + quad * 8);
        } else {
#pragma unroll
          for (int i = 0; i < 8; i++) A[p][kb][i] = 0;
        }
      }
    }

    f4v acc[NT];
#pragma unroll
    for (int t = 0; t < NT; t++) {
      acc[t][0] = bv[t]; acc[t][1] = bv[t]; acc[t][2] = bv[t]; acc[t][3] = bv[t];
    }
#pragma unroll
    for (int p = 0; p < 4; p++)
#pragma unroll
      for (int kb = 0; kb < 2; kb++)
#pragma unroll
        for (int t = 0; t < NT; t++)
          acc[t] = __builtin_amdgcn_mfma_f32_16x16x32_bf16(A[p][kb], B[p][kb][t], acc[t], 0, 0, 0);

#pragma unroll
    for (int t = 0; t < NT; t++) {
#pragma unroll
      for (int r = 0; r < 4; r++) {
        int n2 = nb + quad * 4 + r;
        if (n2 < N) {
          float v = acc[t][r];
          if (DOBN) {
            v = v >= 0.f ? v : 0.01f * v;
            sum_[t] += v;
            sq_[t] += v * v;
          }
          int j = t * 16 + col;
          if (OUTBF) ((u16*)outp)[(size_t)n2 * FOUT + j] = f2b(v);
          else       ((float*)outp)[(size_t)n2 * FOUT + j] = v;
        }
      }
    }
  }

  if (DOBN) {
    float* redS = red;
    float* redQ = red + FOUT * 16;
#pragma unroll
    for (int t = 0; t < NT; t++) {
      redS[(t * 16 + col) * 16 + wv * 4 + quad] = sum_[t];
      redQ[(t * 16 + col) * 16 + wv * 4 + quad] = sq_[t];
    }
    __syncthreads();
    if (tid < FOUT) {
      float a_ = 0.f, b_ = 0.f;
      for (int w = 0; w < 16; w++) { a_ += redS[tid * 16 + w]; b_ += redQ[tid * 16 + w]; }
      atomicAdd(&gs[tid], a_);
      atomicAdd(&gs[64 + tid], b_);
    }
  }
}

// ---------------- merged layer-1 combine (Fin=3, f32 in, bf16 out) + FUSED lrelu/BN-stats ----
// Replaces combine1 + bnstats (saved a full 25.6 MB RW pass over T0).
// Grid-stride 512 blocks (4 waves x 1 node each/iter); stats in registers,
// one LDS reduce + one atomicAdd pair per block (k_combine_m DOBN pattern —
// NOT per-node atomics, which was the k_pool2 contention trap).
// Rounding pipeline bit-identical to old combine1+bnstats:
//   store f2b(acc) -> read b2f -> lrelu -> stats on f32 -> store f2b.
__global__ __launch_bounds__(256) void k_combine1(
    u16* __restrict__ H, const float* __restrict__ x,
    const float* __restrict__ t1, const float* __restrict__ t2,
    const float* __restrict__ t3, const float* __restrict__ W,
    const float* __restrict__ bias, float* __restrict__ gs, int N) {
  __shared__ float ws[768];  // [4][3][64]
  __shared__ float redS[4 * 64], redQ[4 * 64];
  int tid = threadIdx.x;
  for (int i = tid; i < 768; i += 256) ws[i] = W[i];
  int j = tid & 63, wv = tid >> 6;
  float bj = bias[j];
  float sum = 0.f, sq = 0.f;
  __syncthreads();
  const float* xs[4] = {x, t1, t2, t3};
  for (int n = blockIdx.x * 4 + wv; n < N; n += gridDim.x * 4) {
    float acc = bj;
#pragma unroll
    for (int p = 0; p < 4; p++)
#pragma unroll
      for (int i = 0; i < 3; i++)
        acc += xs[p][n * 3 + i] * ws[p * 192 + i * 64 + j];
    float v = b2f(f2b(acc));  // replicate old store-then-reload rounding
    v = v >= 0.f ? v : 0.01f * v;
    sum += v; sq += v * v;
    H[(size_t)n * 64 + j] = f2b(v);
  }
  redS[wv * 64 + j] = sum;
  redQ[wv * 64 + j] = sq;
  __syncthreads();
  if (tid < 64) {
    float a = redS[j] + redS[64 + j] + redS[128 + j] + redS[192 + j];
    float b = redQ[j] + redQ[64 + j] + redQ[128 + j] + redQ[192 + j];
    atomicAdd(&gs[j], a);
    atomicAdd(&gs[64 + j], b);
  }
}

// BN finalize + fold shift into next combine's bias.
// 256 threads (was 64 = ONE wave, 64 serial global loads -> 76 us cold in rocprof):
// k-loop split 4-way across waves (16 loads/thread), LDS reduce.
// ab = (a,b); bias2[j] = bias_next[j] + sum_k b[k] * Wnext0[k*FOUTN + j]
__global__ void k_bnfinal3(const float* __restrict__ gs, const float* __restrict__ g,
                           const float* __restrict__ bt, const float* __restrict__ Wn,
                           const float* __restrict__ bn, float* __restrict__ ab,
                           float* __restrict__ bias2, float Ninv, int FOUTN) {
  int t = threadIdx.x;  // 256
  __shared__ float bsh[64];
  __shared__ float part[4][64];
  if (t < 64) {
    float mu = gs[t] * Ninv;
    float var = gs[64 + t] * Ninv - mu * mu;
    float a = g[t] / sqrtf(var + EPS_BN);
    float b = bt[t] - mu * a;
    ab[t] = a;
    ab[64 + t] = b;
    bsh[t] = b;
  }
  __syncthreads();
  int kq = t >> 6, jl = t & 63;
  for (int j0 = 0; j0 < FOUTN; j0 += 64) {
    int j = j0 + jl;
    float s = 0.f;
    if (j < FOUTN) {
#pragma unroll
      for (int k = 0; k < 16; k++)
        s += bsh[kq * 16 + k] * Wn[(kq * 16 + k) * FOUTN + j];
    }
    part[kq][jl] = s;
    __syncthreads();
    if (kq == 0 && j < FOUTN)
      bias2[j] = bn[j] + part[0][jl] + part[1][jl] + part[2][jl] + part[3][jl];
    __syncthreads();
  }
}

// ---------------- pooling: atomic-free 3-stage (gbound -> chunk partials -> finalize) ----------------
// batch is sorted; 65 binary searches give graph row-ranges. Grid = NG*PM blocks,
// each owns graph g chunk c: register accumulate -> LDS reduce over 8 subgroups ->
// ONE non-atomic 96-float partial write. poolfin2 reduces PM partials per graph.
__global__ void k_gbound(const int* __restrict__ batch, int* __restrict__ gstart,
                         int N, int NG) {
  int g = blockIdx.x * blockDim.x + threadIdx.x;
  if (g > NG) return;
  int lo = 0, hi = N;
  while (lo < hi) {
    int mid = (lo + hi) >> 1;
    if (batch[mid] < g) lo = mid + 1; else hi = mid;
  }
  gstart[g] = lo;
}

__global__ void k_pool3(const float* __restrict__ H, const int* __restrict__ gstart,
                        float* __restrict__ ppart) {
  __shared__ float lsum[8][32], lmax[8][32], lmin[8][32];
  int f = threadIdx.x & 31;
  int sub = threadIdx.x >> 5;
  int g = blockIdx.x / PM, c = blockIdx.x % PM;
  int gs = gstart[g], ge = gstart[g + 1];
  int len = ge - gs;
  int lo = gs + (int)((long long)len * c / PM);
  int hi = gs + (int)((long long)len * (c + 1) / PM);
  float s = 0.f, mx = -3.4e38f, mn = 3.4e38f;
  for (int n = lo + sub; n < hi; n += 8) {
    float v = H[(size_t)n * 32 + f];
    float ss = v * v;
    for (int off = 16; off; off >>= 1) ss += __shfl_xor(ss, off, 32);
    v /= fmaxf(sqrtf(ss), 1e-12f);
    s += v; mx = fmaxf(mx, v); mn = fminf(mn, v);
  }
  lsum[sub][f] = s; lmax[sub][f] = mx; lmin[sub][f] = mn;
  __syncthreads();
  if (sub == 0) {
#pragma unroll
    for (int k = 1; k < 8; k++) {
      s += lsum[k][f];
      mx = fmaxf(mx, lmax[k][f]);
      mn = fminf(mn, lmin[k][f]);
    }
    float* slot = ppart + (size_t)blockIdx.x * 96;
    slot[f] = s; slot[32 + f] = mx; slot[64 + f] = mn;
  }
}

__global__ void k_poolfin2(const float* __restrict__ ppart, const int* __restrict__ gstart,
                           float* __restrict__ out) {
  int g = blockIdx.x, f = threadIdx.x;
  float s = 0.f, mx = -3.4e38f, mn = 3.4e38f;
  for (int c = 0; c < PM; c++) {
    const float* slot = ppart + (size_t)(g * PM + c) * 96;
    s += slot[f];
    mx = fmaxf(mx, slot[32 + f]);
    mn = fminf(mn, slot[64 + f]);
  }
  float cnt = (float)(gstart[g + 1] - gstart[g]);
  float c = fmaxf(cnt, 1.0f);
  out[g * 128 + f] = s / c;
  out[g * 128 + 32 + f] = mx;
  out[g * 128 + 64 + f] = mn;
  out[g * 128 + 96 + f] = s;
}

// ---------------- host ----------------

extern "C" void kernel_launch(void* const* d_in, const int* in_sizes, int n_in,
                              void* d_out, int out_size, void* d_ws, size_t ws_size,
                              hipStream_t stream) {
  const float* x   = (const float*)d_in[0];
  const int*   ei  = (const int*)d_in[1];
  const int*   bat = (const int*)d_in[2];
  const float* W1  = (const float*)d_in[3];  const float* bc1 = (const float*)d_in[4];
  const float* W2  = (const float*)d_in[5];  const float* bc2 = (const float*)d_in[6];
  const float* W3  = (const float*)d_in[7];  const float* bc3 = (const float*)d_in[8];
  const float* W4  = (const float*)d_in[9];  const float* bc4 = (const float*)d_in[10];
  const float* g1  = (const float*)d_in[11]; const float* bt1 = (const float*)d_in[12];
  const float* g2  = (const float*)d_in[13]; const float* bt2 = (const float*)d_in[14];
  const float* g3  = (const float*)d_in[15]; const float* bt3 = (const float*)d_in[16];

  const int N = in_sizes[0] / 3;
  const int E = in_sizes[1] / 2;
  const int NG = out_size / 128;  // out: [NG][128] f32, out_size in ELEMENTS
  const int* src = ei;
  const int* dst = ei + E;
  const size_t Epad = (size_t)E + (size_t)(ROWPAD - 1) * N + 64;

  float* base = (float*)d_ws;
  size_t o = 0;
  auto alloc = [&](size_t n) -> float* {
    float* p = base + o;
    o += (n + 63) & ~(size_t)63;
    return p;
  };
  // zeroed region (contiguous from d_ws start):
  float* bnacc  = alloc(3 * 128);  // per-layer [sum64][sumsq64]
  size_t zero_elems = o;
  // uninitialized (fully overwritten before read):
  int*   gstart = (int*)alloc(NG + 1);
  float* ppart  = alloc((size_t)NG * PM * 96);
  int2*  erec  = (int2*)alloc(2 * Epad);
  float* dinv  = alloc(N);
  int*   hist  = (int*)alloc(N);
  int*   offs  = (int*)alloc(N + 1);
  int*   bsum  = (int*)alloc(256);
  int*   bbase = (int*)alloc(257);
  int*   bcnt  = (int*)alloc(MAXB);
  int*   bbase2 = (int*)alloc(MAXB + 1);
  int*   bcur  = (int*)alloc(MAXB);
  float* ab    = alloc(128);
  float* bias2 = alloc(192);          // L2[64] L3[64] L4[32]
  u16*   wt2   = (u16*)alloc(8192);   // bf16 [4][64][64]
  u16*   wt3   = (u16*)alloc(8192);
  u16*   wt4   = (u16*)alloc(4096);   // bf16 [4][32][64]
  float* t1f   = alloc(3 * (size_t)N);
  float* t2f   = alloc(3 * (size_t)N);
  float* t3f   = alloc(3 * (size_t)N);
  u16*   T0    = (u16*)alloc((size_t)N * 32);  // bf16 [N][64]
  u16*   T1    = (u16*)alloc((size_t)N * 32);
  u16*   T2    = (u16*)alloc((size_t)N * 32);
  u16*   T3    = (u16*)alloc((size_t)N * 32);
  float* C32   = alloc((size_t)N * 32);

  hipMemsetAsync(d_ws, 0, zero_elems * sizeof(float), stream);

  const int NB = (N + 255) / 256;
  const int SB = (N + SC_CHUNK - 1) / SC_CHUNK;
  const int S  = (N + HSEG - 1) / HSEG;
  const int SP = S * HSEG;
  const int NBK = (N + 255) >> 8;
  unsigned* partial = (unsigned*)T0;  // alias
  int2* ebuck = (int2*)T2;            // alias

  k_wprep<<<64, 256, 0, stream>>>(W2, W3, W4, wt2, wt3, wt4);
  k_gbound<<<1, 128, 0, stream>>>(bat, gstart, N, NG);
  k_histseg<<<dim3(S, HC, 2), 256, 0, stream>>>(src, dst, partial, E, SP);
  k_histred<<<NB, 256, 0, stream>>>((const u8*)partial, dinv, hist, N, SP);
  k_scan1<<<SB, 256, 0, stream>>>(hist, bsum, N);
  k_scan2<<<1, 256, 0, stream>>>(bsum, bbase, SB);
  k_scan3<<<SB, 256, 0, stream>>>(hist, bbase, offs, N, SB);
  k_bcnt<<<NBK, 256, 0, stream>>>(hist, bcnt, N);
  k_bscan<<<1, 256, 0, stream>>>(bcnt, bbase2, bcur, NBK);
  k_part<<<512, 256, 0, stream>>>(src, dst, bcur, ebuck, E);
  k_place<<<NBK, 256, 0, stream>>>(ebuck, bbase2, offs, dinv, erec, N);

  const int PB64 = (N * 64 + 255) / 256;
  const int PGB = PB64 < PWB ? PB64 : PWB;  // prop64b grid-stride blocks
  const int TB = (N + 63) / 64;
  const int NCB = TB < 512 ? TB : 512;  // combine grid: 2 blocks/CU, grid-stride over tiles
  const v4i* erec4 = (const v4i*)erec;

  // ---- layer 1: Fin=3 -> 64 (f32 props, merged combine w/ fused lrelu+BN stats) ----
  k_prop3<<<NB, 256, 0, stream>>>(x, nullptr, t1f, offs, erec4, N, 0);
  k_prop3<<<NB, 256, 0, stream>>>(t1f, x, t2f, offs, erec4, N, 1);
  k_prop3<<<NB, 256, 0, stream>>>(t2f, t1f, t3f, offs, erec4, N, 1);
  k_combine1<<<512, 256, 0, stream>>>(T0, x, t1f, t2f, t3f, W1, bc1, bnacc, N);
  k_bnfinal3<<<1, 256, 0, stream>>>(bnacc, g1, bt1, W2, bc2, ab, bias2, 1.0f / N, 64);

  // ---- layer 2 ----
  k_prop64b<<<PGB, 256, 0, stream>>>(T0, ab, nullptr, nullptr, T1, offs, erec4, N, 0);
  k_prop64b<<<PGB, 256, 0, stream>>>(T1, nullptr, T0, ab, T2, offs, erec4, N, 1);
  k_prop64b<<<PGB, 256, 0, stream>>>(T2, nullptr, T1, nullptr, T3, offs, erec4, N, 1);
  k_combine_m<64, true, true><<<NCB, 256, 0, stream>>>(T0, T0, T1, T2, T3, wt2, ab, bias2,
                                                       bnacc + 128, N, TB);
  k_bnfinal3<<<1, 256, 0, stream>>>(bnacc + 128, g2, bt2, W3, bc3, ab, bias2 + 64, 1.0f / N, 64);

  // ---- layer 3 ----
  k_prop64b<<<PGB, 256, 0, stream>>>(T0, ab, nullptr, nullptr, T1, offs, erec4, N, 0);
  k_prop64b<<<PGB, 256, 0, stream>>>(T1, nullptr, T0, ab, T2, offs, erec4, N, 1);
  k_prop64b<<<PGB, 256, 0, stream>>>(T2, nullptr, T1, nullptr, T3, offs, erec4, N, 1);
  k_combine_m<64, true, true><<<NCB, 256, 0, stream>>>(T0, T0, T1, T2, T3, wt3, ab, bias2 + 64,
                                                       bnacc + 256, N, TB);
  k_bnfinal3<<<1, 256, 0, stream>>>(bnacc + 256, g3, bt3, W4, bc4, ab, bias2 + 128, 1.0f / N, 32);

  // ---- layer 4: 64 -> 32 (f32 out C32) ----
  k_prop64b<<<PGB, 256, 0, stream>>>(T0, ab, nullptr, nullptr, T1, offs, erec4, N, 0);
  k_prop64b<<<PGB, 256, 0, stream>>>(T1, nullptr, T0, ab, T2, offs, erec4, N, 1);
  k_prop64b<<<PGB, 256, 0, stream>>>(T2, nullptr, T1, nullptr, T3, offs, erec4, N, 1);
  k_combine_m<32, false, false><<<NCB, 256, 0, stream>>>(C32, T0, T1, T2, T3, wt4, ab, bias2 + 128,
                                                         nullptr, N, TB);

  // ---- pool (L2-normalize fused, atomic-free) ----
  k_pool3<<<NG * PM, 256, 0, stream>>>(C32, gstart, ppart);
  k_poolfin2<<<NG, 32, 0, stream>>>(ppart, gstart, (float*)d_out);
}

// Round 19
// 664.880 us; speedup vs baseline: 1.2734x; 1.2734x over previous
//
#include <hip/hip_runtime.h>

#define EPS_BN 1e-5f
#define ROWPAD 8    // CSR rows padded to multiple of 8 edges (src=0,w=0 filler)
#define HSEG 32768  // histogram bins per segment (packed u8 -> 32 KB LDS)
#define HC 64       // histogram edge-chunks
#define MAXB 512    // max dst-buckets (256 nodes each)
#define PM 24       // pooling chunks per graph (64*24=1536 blocks, ~6/CU)

typedef unsigned short u16;
typedef unsigned char u8;
typedef int v4i __attribute__((ext_vector_type(4)));
typedef short bf8v __attribute__((ext_vector_type(8)));   // 8 bf16 (4 VGPRs) MFMA A/B frag
typedef float f4v __attribute__((ext_vector_type(4)));    // MFMA C/D frag

__device__ __forceinline__ float b2f(u16 u) {
  return __uint_as_float(((unsigned)u) << 16);
}
__device__ __forceinline__ u16 f2b(float f) {  // RTNE
  unsigned u = __float_as_uint(f);
  u += 0x7fffu + ((u >> 16) & 1u);
  return (u16)(u >> 16);
}

// ---------------- preprocessing: packed-u8 LDS segmented histograms ----------------
// int4 vectorized edge loads (latency-bound fix): 8 edges in flight per thread.
__global__ void k_histseg(const int* __restrict__ src, const int* __restrict__ dst,
                          unsigned* __restrict__ partial, int E, int SP) {
  __shared__ unsigned bins[HSEG / 4];
  int s = blockIdx.x, c = blockIdx.y, z = blockIdx.z;
  int t = threadIdx.x;
  for (int i = t; i < HSEG / 4; i += 256) bins[i] = 0;
  __syncthreads();
  const int* keys = z ? dst : src;
  int lo = s * HSEG;

#define UPD(kk) { int k = (kk) - lo; \
    if ((unsigned)k < (unsigned)HSEG) atomicAdd(&bins[k >> 2], 1u << ((k & 3) * 8)); }

  if ((E & 3) == 0) {  // int4 path (dst = ei+E stays 16B-aligned)
    int E4 = E >> 2;
    int ck = (E4 + HC - 1) / HC;
    int i0 = c * ck, i1 = i0 + ck; if (i1 > E4) i1 = E4;
    const int4* k4 = (const int4*)keys;
    int i = i0 + t;
    for (; i + 256 < i1; i += 512) {
      int4 a = k4[i];
      int4 b = k4[i + 256];
      UPD(a.x); UPD(a.y); UPD(a.z); UPD(a.w);
      UPD(b.x); UPD(b.y); UPD(b.z); UPD(b.w);
    }
    if (i < i1) {
      int4 a = k4[i];
      UPD(a.x); UPD(a.y); UPD(a.z); UPD(a.w);
    }
  } else {  // scalar fallback
    int ck = (E + HC - 1) / HC;
    int e0 = c * ck, e1 = e0 + ck; if (e1 > E) e1 = E;
    for (int e = e0 + t; e < e1; e += 256) UPD(keys[e]);
  }
#undef UPD
  __syncthreads();
  unsigned* out = partial + (size_t)(z * HC + c) * (SP >> 2) + (lo >> 2);
  for (int i = t; i < HSEG / 4; i += 256) out[i] = bins[i];
}

__global__ void k_histred(const u8* __restrict__ partial, float* __restrict__ dinv,
                          int* __restrict__ hist, int N, int SP) {
  int n = blockIdx.x * 256 + threadIdx.x;
  if (n >= N) return;
  int a = 0, b = 0;
  for (int c = 0; c < HC; c++) a += partial[(size_t)c * SP + n];
  for (int c = 0; c < HC; c++) b += partial[(size_t)(HC + c) * SP + n];
  dinv[n] = a > 0 ? rsqrtf((float)a) : 0.f;
  hist[n] = b;
}

// ---- hierarchical scan over PADDED counts ----
#define SC_CHUNK 400

__device__ __forceinline__ int lds_incl_scan256(int* lds, int t, int v) {
  lds[t] = v; __syncthreads();
  for (int off = 1; off < 256; off <<= 1) {
    int u = (t >= off) ? lds[t - off] : 0;
    __syncthreads();
    lds[t] += u;
    __syncthreads();
  }
  return lds[t];
}

__device__ __forceinline__ int padcnt(int h) { return (h + (ROWPAD - 1)) & ~(ROWPAD - 1); }

__global__ void k_scan1(const int* __restrict__ hist, int* __restrict__ bsum, int N) {
  __shared__ int lds[256];
  int b = blockIdx.x, t = threadIdx.x;
  int lo = b * SC_CHUNK;
  int hi = lo + SC_CHUNK; if (hi > N) hi = N;
  int i0 = lo + t * 2;
  int s = 0;
  if (i0 < hi) s += padcnt(hist[i0]);
  if (i0 + 1 < hi) s += padcnt(hist[i0 + 1]);
  int incl = lds_incl_scan256(lds, t, s);
  if (t == 255) bsum[b] = incl;
}

__global__ void k_scan2(const int* __restrict__ bsum, int* __restrict__ bbase, int nb) {
  __shared__ int lds[256];
  int t = threadIdx.x;
  int v = (t < nb) ? bsum[t] : 0;
  int incl = lds_incl_scan256(lds, t, v);
  if (t < nb) bbase[t] = incl - v;
  if (t == nb - 1) bbase[nb] = incl;
}

__global__ void k_scan3(const int* __restrict__ hist, const int* __restrict__ bbase,
                        int* __restrict__ offs, int N, int nb) {
  __shared__ int lds[256];
  int b = blockIdx.x, t = threadIdx.x;
  int lo = b * SC_CHUNK;
  int hi = lo + SC_CHUNK; if (hi > N) hi = N;
  int i0 = lo + t * 2;
  int h0 = (i0 < hi) ? padcnt(hist[i0]) : 0;
  int h1 = (i0 + 1 < hi) ? padcnt(hist[i0 + 1]) : 0;
  int s = h0 + h1;
  int incl = lds_incl_scan256(lds, t, s);
  int run = bbase[b] + incl - s;
  if (i0 < hi) offs[i0] = run;
  if (i0 + 1 < hi) offs[i0 + 1] = run + h0;
  if (b == 0 && t == 0) offs[N] = bbase[nb];
}

// ---------------- two-phase binned scatter ----------------
__global__ void k_bcnt(const int* __restrict__ hist, int* __restrict__ bcnt, int N) {
  __shared__ int red[256];
  int b = blockIdx.x, t = threadIdx.x;
  int n = (b << 8) + t;
  red[t] = (n < N) ? hist[n] : 0;
  __syncthreads();
  for (int off = 128; off; off >>= 1) {
    if (t < off) red[t] += red[t + off];
    __syncthreads();
  }
  if (t == 0) bcnt[b] = red[0];
}

__global__ void k_bscan(const int* __restrict__ bcnt, int* __restrict__ bbase2,
                        int* __restrict__ bcur, int nb) {
  __shared__ int lds[256];
  int t = threadIdx.x;
  int i0 = 2 * t, i1 = 2 * t + 1;
  int v0 = (i0 < nb) ? bcnt[i0] : 0;
  int v1 = (i1 < nb) ? bcnt[i1] : 0;
  int s = v0 + v1;
  int incl = lds_incl_scan256(lds, t, s);
  int ex = incl - s;
  if (i0 < nb) { bbase2[i0] = ex; bcur[i0] = ex; }
  if (i1 < nb) { bbase2[i1] = ex + v0; bcur[i1] = ex + v0; }
  if (t == 255) bbase2[nb] = incl;
}

__global__ void k_part(const int* __restrict__ src, const int* __restrict__ dst,
                       int* __restrict__ bcur, int2* __restrict__ ebuck, int E) {
  __shared__ int lcnt[MAXB], lbase[MAXB];
  int t = threadIdx.x;
  for (int i = t; i < MAXB; i += 256) lcnt[i] = 0;
  __syncthreads();
  int ck = (E + gridDim.x - 1) / gridDim.x;
  int e0 = blockIdx.x * ck, e1 = e0 + ck; if (e1 > E) e1 = E;
  for (int e = e0 + t; e < e1; e += 256) atomicAdd(&lcnt[dst[e] >> 8], 1);
  __syncthreads();
  for (int i = t; i < MAXB; i += 256) {
    int c = lcnt[i];
    lbase[i] = c ? atomicAdd(&bcur[i], c) : 0;
    lcnt[i] = 0;
  }
  __syncthreads();
  for (int e = e0 + t; e < e1; e += 256) {
    int d = dst[e];
    int b = d >> 8;
    int ofs = atomicAdd(&lcnt[b], 1);
    int2 r; r.x = src[e]; r.y = d;
    ebuck[lbase[b] + ofs] = r;
  }
}

__global__ void k_place(const int2* __restrict__ ebuck, const int* __restrict__ bbase2,
                        const int* __restrict__ offs, const float* __restrict__ dinv,
                        int2* __restrict__ erec, int N) {
  __shared__ int lcur[256];
  int b = blockIdx.x, t = threadIdx.x;
  lcur[t] = 0;
  __syncthreads();
  int nlo = b << 8;
  int e0 = bbase2[b], e1 = bbase2[b + 1];
  for (int e = e0 + t; e < e1; e += 256) {
    int2 sd = ebuck[e];
    int s = sd.x, d = sd.y;
    int ofs = atomicAdd(&lcur[d - nlo], 1);
    int2 r;
    r.x = s;
    r.y = __float_as_int(-dinv[s] * dinv[d]);
    erec[offs[d] + ofs] = r;
  }
  __syncthreads();
  int n = nlo + t;
  if (n < N) {
    int st = offs[n] + lcur[t];
    int en = offs[n + 1];
    int2 z; z.x = 0; z.y = 0;
    for (int p = st; p < en; p++) erec[p] = z;
  }
}

// ---------------- propagation (padded CSR, bf16 features, scalar record loads) ----------------
__global__ void k_prop64b(const u16* __restrict__ gf, const float* __restrict__ gab,
                          const u16* __restrict__ oldv, const float* __restrict__ oab,
                          u16* __restrict__ outv, const int* __restrict__ offs,
                          const v4i* __restrict__ erec4, int N, int recur) {
  int wid = (blockIdx.x * 256 + threadIdx.x) >> 6;
  int lane = threadIdx.x & 63;
  if (wid >= N) return;
  int row = __builtin_amdgcn_readfirstlane(wid);  // wave-uniform -> scalar loads for records
  int q = offs[row] >> 1, qe = offs[row + 1] >> 1;
  float acc = 0.f, sw = 0.f;
  for (; q + 8 <= qe; q += 8) {  // 16 records
    v4i m[8];
#pragma unroll
    for (int j = 0; j < 8; j++) m[j] = erec4[q + j];
    u16 g[16];
#pragma unroll
    for (int j = 0; j < 8; j++) {
      g[2 * j]     = gf[(size_t)m[j].x * 64 + lane];
      g[2 * j + 1] = gf[(size_t)m[j].z * 64 + lane];
    }
#pragma unroll
    for (int j = 0; j < 8; j++) {
      float w0 = __int_as_float(m[j].y), w1 = __int_as_float(m[j].w);
      acc += w0 * b2f(g[2 * j]) + w1 * b2f(g[2 * j + 1]);
      sw += w0 + w1;
    }
  }
  if (q < qe) {  // exactly 8 records
    v4i m[4];
#pragma unroll
    for (int j = 0; j < 4; j++) m[j] = erec4[q + j];
    u16 g[8];
#pragma unroll
    for (int j = 0; j < 4; j++) {
      g[2 * j]     = gf[(size_t)m[j].x * 64 + lane];
      g[2 * j + 1] = gf[(size_t)m[j].z * 64 + lane];
    }
#pragma unroll
    for (int j = 0; j < 4; j++) {
      float w0 = __int_as_float(m[j].y), w1 = __int_as_float(m[j].w);
      acc += w0 * b2f(g[2 * j]) + w1 * b2f(g[2 * j + 1]);
      sw += w0 + w1;
    }
  }
  float res = acc;
  if (gab) res = gab[lane] * acc + gab[64 + lane] * sw;
  int idx = wid * 64 + lane;
  if (recur) {
    float o = b2f(oldv[idx]);
    if (oab) o = oab[lane] * o + oab[64 + lane];
    res = 2.f * res - o;
  }
  outv[idx] = f2b(res);
}

// F=3 f32 variant (layer 1)
__global__ void k_prop3(const float* __restrict__ gf, const float* __restrict__ oldv,
                        float* __restrict__ outv, const int* __restrict__ offs,
                        const v4i* __restrict__ erec4, int N, int recur) {
  int n = blockIdx.x * 256 + threadIdx.x;
  if (n >= N) return;
  int q = offs[n] >> 1, qe = offs[n + 1] >> 1;
  float a0 = 0.f, a1 = 0.f, a2 = 0.f;
  for (; q < qe; q += 4) {
    v4i m[4];
#pragma unroll
    for (int j = 0; j < 4; j++) m[j] = erec4[q + j];
#pragma unroll
    for (int j = 0; j < 4; j++) {
      float w0 = __int_as_float(m[j].y), w1 = __int_as_float(m[j].w);
      int s0 = m[j].x, s1 = m[j].z;
      a0 += w0 * gf[s0 * 3 + 0] + w1 * gf[s1 * 3 + 0];
      a1 += w0 * gf[s0 * 3 + 1] + w1 * gf[s1 * 3 + 1];
      a2 += w0 * gf[s0 * 3 + 2] + w1 * gf[s1 * 3 + 2];
    }
  }
  if (recur) {
    a0 = 2.f * a0 - oldv[n * 3 + 0];
    a1 = 2.f * a1 - oldv[n * 3 + 1];
    a2 = 2.f * a2 - oldv[n * 3 + 2];
  }
  outv[n * 3 + 0] = a0;
  outv[n * 3 + 1] = a1;
  outv[n * 3 + 2] = a2;
}

// ---------------- weight prep: f32 [4][64][FOUT] -> bf16 [4][FOUT][64] (transposed) ----------------
__global__ void k_wprep(const float* __restrict__ W2, const float* __restrict__ W3,
                        const float* __restrict__ W4, u16* __restrict__ WT2,
                        u16* __restrict__ WT3, u16* __restrict__ WT4) {
  int tid = blockIdx.x * 256 + threadIdx.x;
  if (tid < 16384) {
    int p = tid >> 12, j = (tid >> 6) & 63, k = tid & 63;
    WT2[tid] = f2b(W2[p * 4096 + k * 64 + j]);
    WT3[tid] = f2b(W3[p * 4096 + k * 64 + j]);
  }
  if (tid < 8192) {
    int p = tid >> 11, j = (tid >> 6) & 31, k = tid & 63;
    WT4[tid] = f2b(W4[p * 2048 + k * 32 + j]);
  }
}

// ---------------- MFMA combine: out = bias2 + sum_p Tp @ Wp  (K=256, bf16 MFMA) ----------------
// Weights-stationary: all B-fragments held in registers for the whole kernel
// (FOUT=64: 32 frags = 128 VGPRs). Each block grid-strides over 64-node tiles;
// inner loop = 8 coalesced 16B A-loads + 32 MFMAs, zero LDS traffic.
// BN sum/sumsq accumulate in registers across tiles; one LDS reduce + one
// atomicAdd pair per block at the end.
// A-frag: A[m=lane&15][k=quad*8+j] direct from T tables.
// B-frag: B[k][n=lane&15] from WT (bf16 [4][FOUT][64]); ab folded into p=0.
// C/D: col=lane&15, row=quad*4+reg.
template <int FOUT, bool OUTBF, bool DOBN>
__global__ __launch_bounds__(256, 2) void k_combine_m(
    void* __restrict__ outp, const u16* __restrict__ T0, const u16* __restrict__ T1,
    const u16* __restrict__ T2, const u16* __restrict__ T3, const u16* __restrict__ WTg,
    const float* __restrict__ ab, const float* __restrict__ bias2,
    float* __restrict__ gs, int N, int ntiles) {
  constexpr int NT = FOUT / 16;
  __shared__ float red[2 * FOUT * 16];
  int tid = threadIdx.x;
  int wv = tid >> 6, lane = tid & 63;
  int col = lane & 15, quad = lane >> 4;

  // ---- stage B into registers (weights-stationary), fold a[k] into p==0 ----
  bf8v B[4][2][NT];
#pragma unroll
  for (int p = 0; p < 4; p++) {
#pragma unroll
    for (int kb = 0; kb < 2; kb++) {
      f4v sc0, sc1;
      if (p == 0) {
        sc0 = *(const f4v*)(ab + kb * 32 + quad * 8);
        sc1 = *(const f4v*)(ab + kb * 32 + quad * 8 + 4);
      }
#pragma unroll
      for (int t = 0; t < NT; t++) {
        bf8v b = *(const bf8v*)(WTg + (size_t)(p * FOUT + t * 16 + col) * 64 + kb * 32 + quad * 8);
        if (p == 0) {
#pragma unroll
          for (int i = 0; i < 8; i++) {
            float sc = (i < 4) ? sc0[i] : sc1[i - 4];
            b[i] = (short)f2b(sc * b2f((u16)b[i]));
          }
        }
        B[p][kb][t] = b;
      }
    }
  }

  float bv[NT];
#pragma unroll
  for (int t = 0; t < NT; t++) bv[t] = bias2[t * 16 + col];

  float sum_[NT], sq_[NT];
#pragma unroll
  for (int t = 0; t < NT; t++) { sum_[t] = 0.f; sq_[t] = 0.f; }

  const u16* Tp[4] = {T0, T1, T2, T3};

  for (int tile = blockIdx.x; tile < ntiles; tile += gridDim.x) {
    int nb = tile * 64 + wv * 16;
    int node = nb + col;
    bool valid = node < N;

    bf8v A[4][2];
#pragma unroll
    for (int p = 0; p < 4; p++) {
#pragma unroll
      for (int kb = 0; kb < 2; kb++) {
        if (valid) {
          A[p][kb] = *(const bf8v*)(Tp[p] + (size_t)node * 64 + kb * 32 + quad * 8);
        } else {
#pragma unroll
          for (int i = 0; i < 8; i++) A[p][kb][i] = 0;
        }
      }
    }

    f4v acc[NT];
#pragma unroll
    for (int t = 0; t < NT; t++) {
      acc[t][0] = bv[t]; acc[t][1] = bv[t]; acc[t][2] = bv[t]; acc[t][3] = bv[t];
    }
#pragma unroll
    for (int p = 0; p < 4; p++)
#pragma unroll
      for (int kb = 0; kb < 2; kb++)
#pragma unroll
        for (int t = 0; t < NT; t++)
          acc[t] = __builtin_amdgcn_mfma_f32_16x16x32_bf16(A[p][kb], B[p][kb][t], acc[t], 0, 0, 0);

#pragma unroll
    for (int t = 0; t < NT; t++) {
#pragma unroll
      for (int r = 0; r < 4; r++) {
        int n2 = nb + quad * 4 + r;
        if (n2 < N) {
          float v = acc[t][r];
          if (DOBN) {
            v = v >= 0.f ? v : 0.01f * v;
            sum_[t] += v;
            sq_[t] += v * v;
          }
          int j = t * 16 + col;
          if (OUTBF) ((u16*)outp)[(size_t)n2 * FOUT + j] = f2b(v);
          else       ((float*)outp)[(size_t)n2 * FOUT + j] = v;
        }
      }
    }
  }

  if (DOBN) {
    float* redS = red;
    float* redQ = red + FOUT * 16;
#pragma unroll
    for (int t = 0; t < NT; t++) {
      redS[(t * 16 + col) * 16 + wv * 4 + quad] = sum_[t];
      redQ[(t * 16 + col) * 16 + wv * 4 + quad] = sq_[t];
    }
    __syncthreads();
    if (tid < FOUT) {
      float a_ = 0.f, b_ = 0.f;
      for (int w = 0; w < 16; w++) { a_ += redS[tid * 16 + w]; b_ += redQ[tid * 16 + w]; }
      atomicAdd(&gs[tid], a_);
      atomicAdd(&gs[64 + tid], b_);
    }
  }
}

// ---------------- merged layer-1 combine (Fin=3, f32 in, bf16 out) + FUSED lrelu/BN-stats ----
// Replaces combine1 + bnstats (saved a full 25.6 MB RW pass over T0).
// Grid-stride 512 blocks (4 waves x 1 node each/iter); stats in registers,
// one LDS reduce + one atomicAdd pair per block (k_combine_m DOBN pattern —
// NOT per-node atomics, which was the k_pool2 contention trap).
// Rounding pipeline bit-identical to old combine1+bnstats:
//   store f2b(acc) -> read b2f -> lrelu -> stats on f32 -> store f2b.
__global__ __launch_bounds__(256) void k_combine1(
    u16* __restrict__ H, const float* __restrict__ x,
    const float* __restrict__ t1, const float* __restrict__ t2,
    const float* __restrict__ t3, const float* __restrict__ W,
    const float* __restrict__ bias, float* __restrict__ gs, int N) {
  __shared__ float ws[768];  // [4][3][64]
  __shared__ float redS[4 * 64], redQ[4 * 64];
  int tid = threadIdx.x;
  for (int i = tid; i < 768; i += 256) ws[i] = W[i];
  int j = tid & 63, wv = tid >> 6;
  float bj = bias[j];
  float sum = 0.f, sq = 0.f;
  __syncthreads();
  const float* xs[4] = {x, t1, t2, t3};
  for (int n = blockIdx.x * 4 + wv; n < N; n += gridDim.x * 4) {
    float acc = bj;
#pragma unroll
    for (int p = 0; p < 4; p++)
#pragma unroll
      for (int i = 0; i < 3; i++)
        acc += xs[p][n * 3 + i] * ws[p * 192 + i * 64 + j];
    float v = b2f(f2b(acc));  // replicate old store-then-reload rounding
    v = v >= 0.f ? v : 0.01f * v;
    sum += v; sq += v * v;
    H[(size_t)n * 64 + j] = f2b(v);
  }
  redS[wv * 64 + j] = sum;
  redQ[wv * 64 + j] = sq;
  __syncthreads();
  if (tid < 64) {
    float a = redS[j] + redS[64 + j] + redS[128 + j] + redS[192 + j];
    float b = redQ[j] + redQ[64 + j] + redQ[128 + j] + redQ[192 + j];
    atomicAdd(&gs[j], a);
    atomicAdd(&gs[64 + j], b);
  }
}

// BN finalize + fold shift into next combine's bias.
// 256 threads (was 64 = ONE wave, 64 serial global loads -> 76 us cold in rocprof):
// k-loop split 4-way across waves (16 loads/thread), LDS reduce.
// ab = (a,b); bias2[j] = bias_next[j] + sum_k b[k] * Wnext0[k*FOUTN + j]
__global__ void k_bnfinal3(const float* __restrict__ gs, const float* __restrict__ g,
                           const float* __restrict__ bt, const float* __restrict__ Wn,
                           const float* __restrict__ bn, float* __restrict__ ab,
                           float* __restrict__ bias2, float Ninv, int FOUTN) {
  int t = threadIdx.x;  // 256
  __shared__ float bsh[64];
  __shared__ float part[4][64];
  if (t < 64) {
    float mu = gs[t] * Ninv;
    float var = gs[64 + t] * Ninv - mu * mu;
    float a = g[t] / sqrtf(var + EPS_BN);
    float b = bt[t] - mu * a;
    ab[t] = a;
    ab[64 + t] = b;
    bsh[t] = b;
  }
  __syncthreads();
  int kq = t >> 6, jl = t & 63;
  for (int j0 = 0; j0 < FOUTN; j0 += 64) {
    int j = j0 + jl;
    float s = 0.f;
    if (j < FOUTN) {
#pragma unroll
      for (int k = 0; k < 16; k++)
        s += bsh[kq * 16 + k] * Wn[(kq * 16 + k) * FOUTN + j];
    }
    part[kq][jl] = s;
    __syncthreads();
    if (kq == 0 && j < FOUTN)
      bias2[j] = bn[j] + part[0][jl] + part[1][jl] + part[2][jl] + part[3][jl];
    __syncthreads();
  }
}

// ---------------- pooling: atomic-free 3-stage (gbound -> chunk partials -> finalize) ----------------
// batch is sorted; 65 binary searches give graph row-ranges. Grid = NG*PM blocks,
// each owns graph g chunk c: register accumulate -> LDS reduce over 8 subgroups ->
// ONE non-atomic 96-float partial write. poolfin2 reduces PM partials per graph.
__global__ void k_gbound(const int* __restrict__ batch, int* __restrict__ gstart,
                         int N, int NG) {
  int g = blockIdx.x * blockDim.x + threadIdx.x;
  if (g > NG) return;
  int lo = 0, hi = N;
  while (lo < hi) {
    int mid = (lo + hi) >> 1;
    if (batch[mid] < g) lo = mid + 1; else hi = mid;
  }
  gstart[g] = lo;
}

__global__ void k_pool3(const float* __restrict__ H, const int* __restrict__ gstart,
                        float* __restrict__ ppart) {
  __shared__ float lsum[8][32], lmax[8][32], lmin[8][32];
  int f = threadIdx.x & 31;
  int sub = threadIdx.x >> 5;
  int g = blockIdx.x / PM, c = blockIdx.x % PM;
  int gs = gstart[g], ge = gstart[g + 1];
  int len = ge - gs;
  int lo = gs + (int)((long long)len * c / PM);
  int hi = gs + (int)((long long)len * (c + 1) / PM);
  float s = 0.f, mx = -3.4e38f, mn = 3.4e38f;
  for (int n = lo + sub; n < hi; n += 8) {
    float v = H[(size_t)n * 32 + f];
    float ss = v * v;
    for (int off = 16; off; off >>= 1) ss += __shfl_xor(ss, off, 32);
    v /= fmaxf(sqrtf(ss), 1e-12f);
    s += v; mx = fmaxf(mx, v); mn = fminf(mn, v);
  }
  lsum[sub][f] = s; lmax[sub][f] = mx; lmin[sub][f] = mn;
  __syncthreads();
  if (sub == 0) {
#pragma unroll
    for (int k = 1; k < 8; k++) {
      s += lsum[k][f];
      mx = fmaxf(mx, lmax[k][f]);
      mn = fminf(mn, lmin[k][f]);
    }
    float* slot = ppart + (size_t)blockIdx.x * 96;
    slot[f] = s; slot[32 + f] = mx; slot[64 + f] = mn;
  }
}

__global__ void k_poolfin2(const float* __restrict__ ppart, const int* __restrict__ gstart,
                           float* __restrict__ out) {
  int g = blockIdx.x, f = threadIdx.x;
  float s = 0.f, mx = -3.4e38f, mn = 3.4e38f;
  for (int c = 0; c < PM; c++) {
    const float* slot = ppart + (size_t)(g * PM + c) * 96;
    s += slot[f];
    mx = fmaxf(mx, slot[32 + f]);
    mn = fminf(mn, slot[64 + f]);
  }
  float cnt = (float)(gstart[g + 1] - gstart[g]);
  float c = fmaxf(cnt, 1.0f);
  out[g * 128 + f] = s / c;
  out[g * 128 + 32 + f] = mx;
  out[g * 128 + 64 + f] = mn;
  out[g * 128 + 96 + f] = s;
}

// ---------------- host ----------------

extern "C" void kernel_launch(void* const* d_in, const int* in_sizes, int n_in,
                              void* d_out, int out_size, void* d_ws, size_t ws_size,
                              hipStream_t stream) {
  const float* x   = (const float*)d_in[0];
  const int*   ei  = (const int*)d_in[1];
  const int*   bat = (const int*)d_in[2];
  const float* W1  = (const float*)d_in[3];  const float* bc1 = (const float*)d_in[4];
  const float* W2  = (const float*)d_in[5];  const float* bc2 = (const float*)d_in[6];
  const float* W3  = (const float*)d_in[7];  const float* bc3 = (const float*)d_in[8];
  const float* W4  = (const float*)d_in[9];  const float* bc4 = (const float*)d_in[10];
  const float* g1  = (const float*)d_in[11]; const float* bt1 = (const float*)d_in[12];
  const float* g2  = (const float*)d_in[13]; const float* bt2 = (const float*)d_in[14];
  const float* g3  = (const float*)d_in[15]; const float* bt3 = (const float*)d_in[16];

  const int N = in_sizes[0] / 3;
  const int E = in_sizes[1] / 2;
  const int NG = out_size / 128;  // out: [NG][128] f32, out_size in ELEMENTS
  const int* src = ei;
  const int* dst = ei + E;
  const size_t Epad = (size_t)E + (size_t)(ROWPAD - 1) * N + 64;

  float* base = (float*)d_ws;
  size_t o = 0;
  auto alloc = [&](size_t n) -> float* {
    float* p = base + o;
    o += (n + 63) & ~(size_t)63;
    return p;
  };
  // zeroed region (contiguous from d_ws start):
  float* bnacc  = alloc(3 * 128);  // per-layer [sum64][sumsq64]
  size_t zero_elems = o;
  // uninitialized (fully overwritten before read):
  int*   gstart = (int*)alloc(NG + 1);
  float* ppart  = alloc((size_t)NG * PM * 96);
  int2*  erec  = (int2*)alloc(2 * Epad);
  float* dinv  = alloc(N);
  int*   hist  = (int*)alloc(N);
  int*   offs  = (int*)alloc(N + 1);
  int*   bsum  = (int*)alloc(256);
  int*   bbase = (int*)alloc(257);
  int*   bcnt  = (int*)alloc(MAXB);
  int*   bbase2 = (int*)alloc(MAXB + 1);
  int*   bcur  = (int*)alloc(MAXB);
  float* ab    = alloc(128);
  float* bias2 = alloc(192);          // L2[64] L3[64] L4[32]
  u16*   wt2   = (u16*)alloc(8192);   // bf16 [4][64][64]
  u16*   wt3   = (u16*)alloc(8192);
  u16*   wt4   = (u16*)alloc(4096);   // bf16 [4][32][64]
  float* t1f   = alloc(3 * (size_t)N);
  float* t2f   = alloc(3 * (size_t)N);
  float* t3f   = alloc(3 * (size_t)N);
  u16*   T0    = (u16*)alloc((size_t)N * 32);  // bf16 [N][64]
  u16*   T1    = (u16*)alloc((size_t)N * 32);
  u16*   T2    = (u16*)alloc((size_t)N * 32);
  u16*   T3    = (u16*)alloc((size_t)N * 32);
  float* C32   = alloc((size_t)N * 32);

  hipMemsetAsync(d_ws, 0, zero_elems * sizeof(float), stream);

  const int NB = (N + 255) / 256;
  const int SB = (N + SC_CHUNK - 1) / SC_CHUNK;
  const int S  = (N + HSEG - 1) / HSEG;
  const int SP = S * HSEG;
  const int NBK = (N + 255) >> 8;
  unsigned* partial = (unsigned*)T0;  // alias
  int2* ebuck = (int2*)T2;            // alias

  k_wprep<<<64, 256, 0, stream>>>(W2, W3, W4, wt2, wt3, wt4);
  k_gbound<<<1, 128, 0, stream>>>(bat, gstart, N, NG);
  k_histseg<<<dim3(S, HC, 2), 256, 0, stream>>>(src, dst, partial, E, SP);
  k_histred<<<NB, 256, 0, stream>>>((const u8*)partial, dinv, hist, N, SP);
  k_scan1<<<SB, 256, 0, stream>>>(hist, bsum, N);
  k_scan2<<<1, 256, 0, stream>>>(bsum, bbase, SB);
  k_scan3<<<SB, 256, 0, stream>>>(hist, bbase, offs, N, SB);
  k_bcnt<<<NBK, 256, 0, stream>>>(hist, bcnt, N);
  k_bscan<<<1, 256, 0, stream>>>(bcnt, bbase2, bcur, NBK);
  k_part<<<512, 256, 0, stream>>>(src, dst, bcur, ebuck, E);
  k_place<<<NBK, 256, 0, stream>>>(ebuck, bbase2, offs, dinv, erec, N);

  const int PB64 = (N * 64 + 255) / 256;
  const int TB = (N + 63) / 64;
  const int NCB = TB < 512 ? TB : 512;  // combine grid: 2 blocks/CU, grid-stride over tiles
  const v4i* erec4 = (const v4i*)erec;

  // ---- layer 1: Fin=3 -> 64 (f32 props, merged combine w/ fused lrelu+BN stats) ----
  k_prop3<<<NB, 256, 0, stream>>>(x, nullptr, t1f, offs, erec4, N, 0);
  k_prop3<<<NB, 256, 0, stream>>>(t1f, x, t2f, offs, erec4, N, 1);
  k_prop3<<<NB, 256, 0, stream>>>(t2f, t1f, t3f, offs, erec4, N, 1);
  k_combine1<<<512, 256, 0, stream>>>(T0, x, t1f, t2f, t3f, W1, bc1, bnacc, N);
  k_bnfinal3<<<1, 256, 0, stream>>>(bnacc, g1, bt1, W2, bc2, ab, bias2, 1.0f / N, 64);

  // ---- layer 2 ----
  k_prop64b<<<PB64, 256, 0, stream>>>(T0, ab, nullptr, nullptr, T1, offs, erec4, N, 0);
  k_prop64b<<<PB64, 256, 0, stream>>>(T1, nullptr, T0, ab, T2, offs, erec4, N, 1);
  k_prop64b<<<PB64, 256, 0, stream>>>(T2, nullptr, T1, nullptr, T3, offs, erec4, N, 1);
  k_combine_m<64, true, true><<<NCB, 256, 0, stream>>>(T0, T0, T1, T2, T3, wt2, ab, bias2,
                                                       bnacc + 128, N, TB);
  k_bnfinal3<<<1, 256, 0, stream>>>(bnacc + 128, g2, bt2, W3, bc3, ab, bias2 + 64, 1.0f / N, 64);

  // ---- layer 3 ----
  k_prop64b<<<PB64, 256, 0, stream>>>(T0, ab, nullptr, nullptr, T1, offs, erec4, N, 0);
  k_prop64b<<<PB64, 256, 0, stream>>>(T1, nullptr, T0, ab, T2, offs, erec4, N, 1);
  k_prop64b<<<PB64, 256, 0, stream>>>(T2, nullptr, T1, nullptr, T3, offs, erec4, N, 1);
  k_combine_m<64, true, true><<<NCB, 256, 0, stream>>>(T0, T0, T1, T2, T3, wt3, ab, bias2 + 64,
                                                       bnacc + 256, N, TB);
  k_bnfinal3<<<1, 256, 0, stream>>>(bnacc + 256, g3, bt3, W4, bc4, ab, bias2 + 128, 1.0f / N, 32);

  // ---- layer 4: 64 -> 32 (f32 out C32) ----
  k_prop64b<<<PB64, 256, 0, stream>>>(T0, ab, nullptr, nullptr, T1, offs, erec4, N, 0);
  k_prop64b<<<PB64, 256, 0, stream>>>(T1, nullptr, T0, ab, T2, offs, erec4, N, 1);
  k_prop64b<<<PB64, 256, 0, stream>>>(T2, nullptr, T1, nullptr, T3, offs, erec4, N, 1);
  k_combine_m<32, false, false><<<NCB, 256, 0, stream>>>(C32, T0, T1, T2, T3, wt4, ab, bias2 + 128,
                                                         nullptr, N, TB);

  // ---- pool (L2-normalize fused, atomic-free) ----
  k_pool3<<<NG * PM, 256, 0, stream>>>(C32, gstart, ppart);
  k_poolfin2<<<NG, 32, 0, stream>>>(ppart, gstart, (float*)d_out);
}

// Round 20
// 651.543 us; speedup vs baseline: 1.2994x; 1.0205x over previous
//
#include <hip/hip_runtime.h>

#define EPS_BN 1e-5f
#define ROWPAD 8    // CSR rows padded to multiple of 8 edges (src=0,w=0 filler)
#define HSEG 32768  // histogram bins per segment (packed u8 -> 32 KB LDS)
#define HC 64       // histogram edge-chunks
#define MAXB 512    // max dst-buckets (256 nodes each)
#define PM 24       // pooling chunks per graph (64*24=1536 blocks, ~6/CU)

typedef unsigned short u16;
typedef unsigned char u8;
typedef int v4i __attribute__((ext_vector_type(4)));
typedef short bf8v __attribute__((ext_vector_type(8)));   // 8 bf16 (4 VGPRs) MFMA A/B frag
typedef float f4v __attribute__((ext_vector_type(4)));    // MFMA C/D frag

__device__ __forceinline__ float b2f(u16 u) {
  return __uint_as_float(((unsigned)u) << 16);
}
__device__ __forceinline__ u16 f2b(float f) {  // RTNE
  unsigned u = __float_as_uint(f);
  u += 0x7fffu + ((u >> 16) & 1u);
  return (u16)(u >> 16);
}

// ---------------- preprocessing: packed-u8 LDS segmented histograms ----------------
// int4 vectorized edge loads (latency-bound fix): 8 edges in flight per thread.
__global__ void k_histseg(const int* __restrict__ src, const int* __restrict__ dst,
                          unsigned* __restrict__ partial, int E, int SP) {
  __shared__ unsigned bins[HSEG / 4];
  int s = blockIdx.x, c = blockIdx.y, z = blockIdx.z;
  int t = threadIdx.x;
  for (int i = t; i < HSEG / 4; i += 256) bins[i] = 0;
  __syncthreads();
  const int* keys = z ? dst : src;
  int lo = s * HSEG;

#define UPD(kk) { int k = (kk) - lo; \
    if ((unsigned)k < (unsigned)HSEG) atomicAdd(&bins[k >> 2], 1u << ((k & 3) * 8)); }

  if ((E & 3) == 0) {  // int4 path (dst = ei+E stays 16B-aligned)
    int E4 = E >> 2;
    int ck = (E4 + HC - 1) / HC;
    int i0 = c * ck, i1 = i0 + ck; if (i1 > E4) i1 = E4;
    const int4* k4 = (const int4*)keys;
    int i = i0 + t;
    for (; i + 256 < i1; i += 512) {
      int4 a = k4[i];
      int4 b = k4[i + 256];
      UPD(a.x); UPD(a.y); UPD(a.z); UPD(a.w);
      UPD(b.x); UPD(b.y); UPD(b.z); UPD(b.w);
    }
    if (i < i1) {
      int4 a = k4[i];
      UPD(a.x); UPD(a.y); UPD(a.z); UPD(a.w);
    }
  } else {  // scalar fallback
    int ck = (E + HC - 1) / HC;
    int e0 = c * ck, e1 = e0 + ck; if (e1 > E) e1 = E;
    for (int e = e0 + t; e < e1; e += 256) UPD(keys[e]);
  }
#undef UPD
  __syncthreads();
  unsigned* out = partial + (size_t)(z * HC + c) * (SP >> 2) + (lo >> 2);
  for (int i = t; i < HSEG / 4; i += 256) out[i] = bins[i];
}

__global__ void k_histred(const u8* __restrict__ partial, float* __restrict__ dinv,
                          int* __restrict__ hist, int N, int SP) {
  int n = blockIdx.x * 256 + threadIdx.x;
  if (n >= N) return;
  int a = 0, b = 0;
  for (int c = 0; c < HC; c++) a += partial[(size_t)c * SP + n];
  for (int c = 0; c < HC; c++) b += partial[(size_t)(HC + c) * SP + n];
  dinv[n] = a > 0 ? rsqrtf((float)a) : 0.f;
  hist[n] = b;
}

// ---- hierarchical scan over PADDED counts ----
#define SC_CHUNK 400

__device__ __forceinline__ int lds_incl_scan256(int* lds, int t, int v) {
  lds[t] = v; __syncthreads();
  for (int off = 1; off < 256; off <<= 1) {
    int u = (t >= off) ? lds[t - off] : 0;
    __syncthreads();
    lds[t] += u;
    __syncthreads();
  }
  return lds[t];
}

__device__ __forceinline__ int padcnt(int h) { return (h + (ROWPAD - 1)) & ~(ROWPAD - 1); }

__global__ void k_scan1(const int* __restrict__ hist, int* __restrict__ bsum, int N) {
  __shared__ int lds[256];
  int b = blockIdx.x, t = threadIdx.x;
  int lo = b * SC_CHUNK;
  int hi = lo + SC_CHUNK; if (hi > N) hi = N;
  int i0 = lo + t * 2;
  int s = 0;
  if (i0 < hi) s += padcnt(hist[i0]);
  if (i0 + 1 < hi) s += padcnt(hist[i0 + 1]);
  int incl = lds_incl_scan256(lds, t, s);
  if (t == 255) bsum[b] = incl;
}

__global__ void k_scan2(const int* __restrict__ bsum, int* __restrict__ bbase, int nb) {
  __shared__ int lds[256];
  int t = threadIdx.x;
  int v = (t < nb) ? bsum[t] : 0;
  int incl = lds_incl_scan256(lds, t, v);
  if (t < nb) bbase[t] = incl - v;
  if (t == nb - 1) bbase[nb] = incl;
}

__global__ void k_scan3(const int* __restrict__ hist, const int* __restrict__ bbase,
                        int* __restrict__ offs, int N, int nb) {
  __shared__ int lds[256];
  int b = blockIdx.x, t = threadIdx.x;
  int lo = b * SC_CHUNK;
  int hi = lo + SC_CHUNK; if (hi > N) hi = N;
  int i0 = lo + t * 2;
  int h0 = (i0 < hi) ? padcnt(hist[i0]) : 0;
  int h1 = (i0 + 1 < hi) ? padcnt(hist[i0 + 1]) : 0;
  int s = h0 + h1;
  int incl = lds_incl_scan256(lds, t, s);
  int run = bbase[b] + incl - s;
  if (i0 < hi) offs[i0] = run;
  if (i0 + 1 < hi) offs[i0 + 1] = run + h0;
  if (b == 0 && t == 0) offs[N] = bbase[nb];
}

// ---------------- two-phase binned scatter ----------------
__global__ void k_bcnt(const int* __restrict__ hist, int* __restrict__ bcnt, int N) {
  __shared__ int red[256];
  int b = blockIdx.x, t = threadIdx.x;
  int n = (b << 8) + t;
  red[t] = (n < N) ? hist[n] : 0;
  __syncthreads();
  for (int off = 128; off; off >>= 1) {
    if (t < off) red[t] += red[t + off];
    __syncthreads();
  }
  if (t == 0) bcnt[b] = red[0];
}

__global__ void k_bscan(const int* __restrict__ bcnt, int* __restrict__ bbase2,
                        int* __restrict__ bcur, int nb) {
  __shared__ int lds[256];
  int t = threadIdx.x;
  int i0 = 2 * t, i1 = 2 * t + 1;
  int v0 = (i0 < nb) ? bcnt[i0] : 0;
  int v1 = (i1 < nb) ? bcnt[i1] : 0;
  int s = v0 + v1;
  int incl = lds_incl_scan256(lds, t, s);
  int ex = incl - s;
  if (i0 < nb) { bbase2[i0] = ex; bcur[i0] = ex; }
  if (i1 < nb) { bbase2[i1] = ex + v0; bcur[i1] = ex + v0; }
  if (t == 255) bbase2[nb] = incl;
}

__global__ void k_part(const int* __restrict__ src, const int* __restrict__ dst,
                       int* __restrict__ bcur, int2* __restrict__ ebuck, int E) {
  __shared__ int lcnt[MAXB], lbase[MAXB];
  int t = threadIdx.x;
  for (int i = t; i < MAXB; i += 256) lcnt[i] = 0;
  __syncthreads();
  int ck = (E + gridDim.x - 1) / gridDim.x;
  int e0 = blockIdx.x * ck, e1 = e0 + ck; if (e1 > E) e1 = E;
  for (int e = e0 + t; e < e1; e += 256) atomicAdd(&lcnt[dst[e] >> 8], 1);
  __syncthreads();
  for (int i = t; i < MAXB; i += 256) {
    int c = lcnt[i];
    lbase[i] = c ? atomicAdd(&bcur[i], c) : 0;
    lcnt[i] = 0;
  }
  __syncthreads();
  for (int e = e0 + t; e < e1; e += 256) {
    int d = dst[e];
    int b = d >> 8;
    int ofs = atomicAdd(&lcnt[b], 1);
    int2 r; r.x = src[e]; r.y = d;
    ebuck[lbase[b] + ofs] = r;
  }
}

__global__ void k_place(const int2* __restrict__ ebuck, const int* __restrict__ bbase2,
                        const int* __restrict__ offs, const float* __restrict__ dinv,
                        int2* __restrict__ erec, int N) {
  __shared__ int lcur[256];
  int b = blockIdx.x, t = threadIdx.x;
  lcur[t] = 0;
  __syncthreads();
  int nlo = b << 8;
  int e0 = bbase2[b], e1 = bbase2[b + 1];
  for (int e = e0 + t; e < e1; e += 256) {
    int2 sd = ebuck[e];
    int s = sd.x, d = sd.y;
    int ofs = atomicAdd(&lcur[d - nlo], 1);
    int2 r;
    r.x = s;
    r.y = __float_as_int(-dinv[s] * dinv[d]);
    erec[offs[d] + ofs] = r;
  }
  __syncthreads();
  int n = nlo + t;
  if (n < N) {
    int st = offs[n] + lcur[t];
    int en = offs[n + 1];
    int2 z; z.x = 0; z.y = 0;
    for (int p = st; p < en; p++) erec[p] = z;
  }
}

// ---------------- propagation (padded CSR, bf16 features, scalar record loads) ----------------
// Template-specialized on (GAB, RECUR, OAB): gab/oab were runtime pointers, so the
// compiler could not DCE the sw accumulation (2 VALU adds/record ~= 1/3 of FMA work)
// on the 6-of-9 launches that never use it. Compile-time split removes it; per-node
// arithmetic sequence is unchanged (sw only feeds the GAB path). One-shot structure,
// grid, and memory layout identical to the verified 664.9 us baseline.
template <int GAB, int RECUR, int OAB>
__global__ void k_prop64b(const u16* __restrict__ gf, const float* __restrict__ gab,
                          const u16* __restrict__ oldv, const float* __restrict__ oab,
                          u16* __restrict__ outv, const int* __restrict__ offs,
                          const v4i* __restrict__ erec4, int N) {
  int wid = (blockIdx.x * 256 + threadIdx.x) >> 6;
  int lane = threadIdx.x & 63;
  if (wid >= N) return;
  int row = __builtin_amdgcn_readfirstlane(wid);  // wave-uniform -> scalar loads for records
  int q = offs[row] >> 1, qe = offs[row + 1] >> 1;
  float acc = 0.f, sw = 0.f;
  for (; q + 8 <= qe; q += 8) {  // 16 records
    v4i m[8];
#pragma unroll
    for (int j = 0; j < 8; j++) m[j] = erec4[q + j];
    u16 g[16];
#pragma unroll
    for (int j = 0; j < 8; j++) {
      g[2 * j]     = gf[(size_t)m[j].x * 64 + lane];
      g[2 * j + 1] = gf[(size_t)m[j].z * 64 + lane];
    }
#pragma unroll
    for (int j = 0; j < 8; j++) {
      float w0 = __int_as_float(m[j].y), w1 = __int_as_float(m[j].w);
      acc += w0 * b2f(g[2 * j]) + w1 * b2f(g[2 * j + 1]);
      if (GAB) sw += w0 + w1;
    }
  }
  if (q < qe) {  // exactly 8 records
    v4i m[4];
#pragma unroll
    for (int j = 0; j < 4; j++) m[j] = erec4[q + j];
    u16 g[8];
#pragma unroll
    for (int j = 0; j < 4; j++) {
      g[2 * j]     = gf[(size_t)m[j].x * 64 + lane];
      g[2 * j + 1] = gf[(size_t)m[j].z * 64 + lane];
    }
#pragma unroll
    for (int j = 0; j < 4; j++) {
      float w0 = __int_as_float(m[j].y), w1 = __int_as_float(m[j].w);
      acc += w0 * b2f(g[2 * j]) + w1 * b2f(g[2 * j + 1]);
      if (GAB) sw += w0 + w1;
    }
  }
  float res = acc;
  if (GAB) res = gab[lane] * acc + gab[64 + lane] * sw;
  int idx = wid * 64 + lane;
  if (RECUR) {
    float o = b2f(oldv[idx]);
    if (OAB) o = oab[lane] * o + oab[64 + lane];
    res = 2.f * res - o;
  }
  outv[idx] = f2b(res);
}

// F=3 f32 variant (layer 1)
__global__ void k_prop3(const float* __restrict__ gf, const float* __restrict__ oldv,
                        float* __restrict__ outv, const int* __restrict__ offs,
                        const v4i* __restrict__ erec4, int N, int recur) {
  int n = blockIdx.x * 256 + threadIdx.x;
  if (n >= N) return;
  int q = offs[n] >> 1, qe = offs[n + 1] >> 1;
  float a0 = 0.f, a1 = 0.f, a2 = 0.f;
  for (; q < qe; q += 4) {
    v4i m[4];
#pragma unroll
    for (int j = 0; j < 4; j++) m[j] = erec4[q + j];
#pragma unroll
    for (int j = 0; j < 4; j++) {
      float w0 = __int_as_float(m[j].y), w1 = __int_as_float(m[j].w);
      int s0 = m[j].x, s1 = m[j].z;
      a0 += w0 * gf[s0 * 3 + 0] + w1 * gf[s1 * 3 + 0];
      a1 += w0 * gf[s0 * 3 + 1] + w1 * gf[s1 * 3 + 1];
      a2 += w0 * gf[s0 * 3 + 2] + w1 * gf[s1 * 3 + 2];
    }
  }
  if (recur) {
    a0 = 2.f * a0 - oldv[n * 3 + 0];
    a1 = 2.f * a1 - oldv[n * 3 + 1];
    a2 = 2.f * a2 - oldv[n * 3 + 2];
  }
  outv[n * 3 + 0] = a0;
  outv[n * 3 + 1] = a1;
  outv[n * 3 + 2] = a2;
}

// ---------------- weight prep: f32 [4][64][FOUT] -> bf16 [4][FOUT][64] (transposed) ----------------
__global__ void k_wprep(const float* __restrict__ W2, const float* __restrict__ W3,
                        const float* __restrict__ W4, u16* __restrict__ WT2,
                        u16* __restrict__ WT3, u16* __restrict__ WT4) {
  int tid = blockIdx.x * 256 + threadIdx.x;
  if (tid < 16384) {
    int p = tid >> 12, j = (tid >> 6) & 63, k = tid & 63;
    WT2[tid] = f2b(W2[p * 4096 + k * 64 + j]);
    WT3[tid] = f2b(W3[p * 4096 + k * 64 + j]);
  }
  if (tid < 8192) {
    int p = tid >> 11, j = (tid >> 6) & 31, k = tid & 63;
    WT4[tid] = f2b(W4[p * 2048 + k * 32 + j]);
  }
}

// ---------------- MFMA combine: out = bias2 + sum_p Tp @ Wp  (K=256, bf16 MFMA) ----------------
// Weights-stationary: all B-fragments held in registers for the whole kernel
// (FOUT=64: 32 frags = 128 VGPRs). Each block grid-strides over 64-node tiles;
// inner loop = 8 coalesced 16B A-loads + 32 MFMAs, zero LDS traffic.
// BN sum/sumsq accumulate in registers across tiles; one LDS reduce + one
// atomicAdd pair per block at the end.
// A-frag: A[m=lane&15][k=quad*8+j] direct from T tables.
// B-frag: B[k][n=lane&15] from WT (bf16 [4][FOUT][64]); ab folded into p=0.
// C/D: col=lane&15, row=quad*4+reg.
template <int FOUT, bool OUTBF, bool DOBN>
__global__ __launch_bounds__(256, 2) void k_combine_m(
    void* __restrict__ outp, const u16* __restrict__ T0, const u16* __restrict__ T1,
    const u16* __restrict__ T2, const u16* __restrict__ T3, const u16* __restrict__ WTg,
    const float* __restrict__ ab, const float* __restrict__ bias2,
    float* __restrict__ gs, int N, int ntiles) {
  constexpr int NT = FOUT / 16;
  __shared__ float red[2 * FOUT * 16];
  int tid = threadIdx.x;
  int wv = tid >> 6, lane = tid & 63;
  int col = lane & 15, quad = lane >> 4;

  // ---- stage B into registers (weights-stationary), fold a[k] into p==0 ----
  bf8v B[4][2][NT];
#pragma unroll
  for (int p = 0; p < 4; p++) {
#pragma unroll
    for (int kb = 0; kb < 2; kb++) {
      f4v sc0, sc1;
      if (p == 0) {
        sc0 = *(const f4v*)(ab + kb * 32 + quad * 8);
        sc1 = *(const f4v*)(ab + kb * 32 + quad * 8 + 4);
      }
#pragma unroll
      for (int t = 0; t < NT; t++) {
        bf8v b = *(const bf8v*)(WTg + (size_t)(p * FOUT + t * 16 + col) * 64 + kb * 32 + quad * 8);
        if (p == 0) {
#pragma unroll
          for (int i = 0; i < 8; i++) {
            float sc = (i < 4) ? sc0[i] : sc1[i - 4];
            b[i] = (short)f2b(sc * b2f((u16)b[i]));
          }
        }
        B[p][kb][t] = b;
      }
    }
  }

  float bv[NT];
#pragma unroll
  for (int t = 0; t < NT; t++) bv[t] = bias2[t * 16 + col];

  float sum_[NT], sq_[NT];
#pragma unroll
  for (int t = 0; t < NT; t++) { sum_[t] = 0.f; sq_[t] = 0.f; }

  const u16* Tp[4] = {T0, T1, T2, T3};

  for (int tile = blockIdx.x; tile < ntiles; tile += gridDim.x) {
    int nb = tile * 64 + wv * 16;
    int node = nb + col;
    bool valid = node < N;

    bf8v A[4][2];
#pragma unroll
    for (int p = 0; p < 4; p++) {
#pragma unroll
      for (int kb = 0; kb < 2; kb++) {
        if (valid) {
          A[p][kb] = *(const bf8v*)(Tp[p] + (size_t)node * 64 + kb * 32 + quad * 8);
        } else {
#pragma unroll
          for (int i = 0; i < 8; i++) A[p][kb][i] = 0;
        }
      }
    }

    f4v acc[NT];
#pragma unroll
    for (int t = 0; t < NT; t++) {
      acc[t][0] = bv[t]; acc[t][1] = bv[t]; acc[t][2] = bv[t]; acc[t][3] = bv[t];
    }
#pragma unroll
    for (int p = 0; p < 4; p++)
#pragma unroll
      for (int kb = 0; kb < 2; kb++)
#pragma unroll
        for (int t = 0; t < NT; t++)
          acc[t] = __builtin_amdgcn_mfma_f32_16x16x32_bf16(A[p][kb], B[p][kb][t], acc[t], 0, 0, 0);

#pragma unroll
    for (int t = 0; t < NT; t++) {
#pragma unroll
      for (int r = 0; r < 4; r++) {
        int n2 = nb + quad * 4 + r;
        if (n2 < N) {
          float v = acc[t][r];
          if (DOBN) {
            v = v >= 0.f ? v : 0.01f * v;
            sum_[t] += v;
            sq_[t] += v * v;
          }
          int j = t * 16 + col;
          if (OUTBF) ((u16*)outp)[(size_t)n2 * FOUT + j] = f2b(v);
          else       ((float*)outp)[(size_t)n2 * FOUT + j] = v;
        }
      }
    }
  }

  if (DOBN) {
    float* redS = red;
    float* redQ = red + FOUT * 16;
#pragma unroll
    for (int t = 0; t < NT; t++) {
      redS[(t * 16 + col) * 16 + wv * 4 + quad] = sum_[t];
      redQ[(t * 16 + col) * 16 + wv * 4 + quad] = sq_[t];
    }
    __syncthreads();
    if (tid < FOUT) {
      float a_ = 0.f, b_ = 0.f;
      for (int w = 0; w < 16; w++) { a_ += redS[tid * 16 + w]; b_ += redQ[tid * 16 + w]; }
      atomicAdd(&gs[tid], a_);
      atomicAdd(&gs[64 + tid], b_);
    }
  }
}

// ---------------- merged layer-1 combine (Fin=3, f32 in, bf16 out) + FUSED lrelu/BN-stats ----
// Replaces combine1 + bnstats (saved a full 25.6 MB RW pass over T0).
// Grid-stride 512 blocks (4 waves x 1 node each/iter); stats in registers,
// one LDS reduce + one atomicAdd pair per block (k_combine_m DOBN pattern —
// NOT per-node atomics, which was the k_pool2 contention trap).
// Rounding pipeline bit-identical to old combine1+bnstats:
//   store f2b(acc) -> read b2f -> lrelu -> stats on f32 -> store f2b.
__global__ __launch_bounds__(256) void k_combine1(
    u16* __restrict__ H, const float* __restrict__ x,
    const float* __restrict__ t1, const float* __restrict__ t2,
    const float* __restrict__ t3, const float* __restrict__ W,
    const float* __restrict__ bias, float* __restrict__ gs, int N) {
  __shared__ float ws[768];  // [4][3][64]
  __shared__ float redS[4 * 64], redQ[4 * 64];
  int tid = threadIdx.x;
  for (int i = tid; i < 768; i += 256) ws[i] = W[i];
  int j = tid & 63, wv = tid >> 6;
  float bj = bias[j];
  float sum = 0.f, sq = 0.f;
  __syncthreads();
  const float* xs[4] = {x, t1, t2, t3};
  for (int n = blockIdx.x * 4 + wv; n < N; n += gridDim.x * 4) {
    float acc = bj;
#pragma unroll
    for (int p = 0; p < 4; p++)
#pragma unroll
      for (int i = 0; i < 3; i++)
        acc += xs[p][n * 3 + i] * ws[p * 192 + i * 64 + j];
    float v = b2f(f2b(acc));  // replicate old store-then-reload rounding
    v = v >= 0.f ? v : 0.01f * v;
    sum += v; sq += v * v;
    H[(size_t)n * 64 + j] = f2b(v);
  }
  redS[wv * 64 + j] = sum;
  redQ[wv * 64 + j] = sq;
  __syncthreads();
  if (tid < 64) {
    float a = redS[j] + redS[64 + j] + redS[128 + j] + redS[192 + j];
    float b = redQ[j] + redQ[64 + j] + redQ[128 + j] + redQ[192 + j];
    atomicAdd(&gs[j], a);
    atomicAdd(&gs[64 + j], b);
  }
}

// BN finalize + fold shift into next combine's bias.
// 256 threads (was 64 = ONE wave, 64 serial global loads -> 76 us cold in rocprof):
// k-loop split 4-way across waves (16 loads/thread), LDS reduce.
// ab = (a,b); bias2[j] = bias_next[j] + sum_k b[k] * Wnext0[k*FOUTN + j]
__global__ void k_bnfinal3(const float* __restrict__ gs, const float* __restrict__ g,
                           const float* __restrict__ bt, const float* __restrict__ Wn,
                           const float* __restrict__ bn, float* __restrict__ ab,
                           float* __restrict__ bias2, float Ninv, int FOUTN) {
  int t = threadIdx.x;  // 256
  __shared__ float bsh[64];
  __shared__ float part[4][64];
  if (t < 64) {
    float mu = gs[t] * Ninv;
    float var = gs[64 + t] * Ninv - mu * mu;
    float a = g[t] / sqrtf(var + EPS_BN);
    float b = bt[t] - mu * a;
    ab[t] = a;
    ab[64 + t] = b;
    bsh[t] = b;
  }
  __syncthreads();
  int kq = t >> 6, jl = t & 63;
  for (int j0 = 0; j0 < FOUTN; j0 += 64) {
    int j = j0 + jl;
    float s = 0.f;
    if (j < FOUTN) {
#pragma unroll
      for (int k = 0; k < 16; k++)
        s += bsh[kq * 16 + k] * Wn[(kq * 16 + k) * FOUTN + j];
    }
    part[kq][jl] = s;
    __syncthreads();
    if (kq == 0 && j < FOUTN)
      bias2[j] = bn[j] + part[0][jl] + part[1][jl] + part[2][jl] + part[3][jl];
    __syncthreads();
  }
}

// ---------------- pooling: atomic-free 3-stage (gbound -> chunk partials -> finalize) ----------------
// batch is sorted; 65 binary searches give graph row-ranges. Grid = NG*PM blocks,
// each owns graph g chunk c: register accumulate -> LDS reduce over 8 subgroups ->
// ONE non-atomic 96-float partial write. poolfin2 reduces PM partials per graph.
__global__ void k_gbound(const int* __restrict__ batch, int* __restrict__ gstart,
                         int N, int NG) {
  int g = blockIdx.x * blockDim.x + threadIdx.x;
  if (g > NG) return;
  int lo = 0, hi = N;
  while (lo < hi) {
    int mid = (lo + hi) >> 1;
    if (batch[mid] < g) lo = mid + 1; else hi = mid;
  }
  gstart[g] = lo;
}

__global__ void k_pool3(const float* __restrict__ H, const int* __restrict__ gstart,
                        float* __restrict__ ppart) {
  __shared__ float lsum[8][32], lmax[8][32], lmin[8][32];
  int f = threadIdx.x & 31;
  int sub = threadIdx.x >> 5;
  int g = blockIdx.x / PM, c = blockIdx.x % PM;
  int gs = gstart[g], ge = gstart[g + 1];
  int len = ge - gs;
  int lo = gs + (int)((long long)len * c / PM);
  int hi = gs + (int)((long long)len * (c + 1) / PM);
  float s = 0.f, mx = -3.4e38f, mn = 3.4e38f;
  for (int n = lo + sub; n < hi; n += 8) {
    float v = H[(size_t)n * 32 + f];
    float ss = v * v;
    for (int off = 16; off; off >>= 1) ss += __shfl_xor(ss, off, 32);
    v /= fmaxf(sqrtf(ss), 1e-12f);
    s += v; mx = fmaxf(mx, v); mn = fminf(mn, v);
  }
  lsum[sub][f] = s; lmax[sub][f] = mx; lmin[sub][f] = mn;
  __syncthreads();
  if (sub == 0) {
#pragma unroll
    for (int k = 1; k < 8; k++) {
      s += lsum[k][f];
      mx = fmaxf(mx, lmax[k][f]);
      mn = fminf(mn, lmin[k][f]);
    }
    float* slot = ppart + (size_t)blockIdx.x * 96;
    slot[f] = s; slot[32 + f] = mx; slot[64 + f] = mn;
  }
}

__global__ void k_poolfin2(const float* __restrict__ ppart, const int* __restrict__ gstart,
                           float* __restrict__ out) {
  int g = blockIdx.x, f = threadIdx.x;
  float s = 0.f, mx = -3.4e38f, mn = 3.4e38f;
  for (int c = 0; c < PM; c++) {
    const float* slot = ppart + (size_t)(g * PM + c) * 96;
    s += slot[f];
    mx = fmaxf(mx, slot[32 + f]);
    mn = fminf(mn, slot[64 + f]);
  }
  float cnt = (float)(gstart[g + 1] - gstart[g]);
  float c = fmaxf(cnt, 1.0f);
  out[g * 128 + f] = s / c;
  out[g * 128 + 32 + f] = mx;
  out[g * 128 + 64 + f] = mn;
  out[g * 128 + 96 + f] = s;
}

// ---------------- host ----------------

extern "C" void kernel_launch(void* const* d_in, const int* in_sizes, int n_in,
                              void* d_out, int out_size, void* d_ws, size_t ws_size,
                              hipStream_t stream) {
  const float* x   = (const float*)d_in[0];
  const int*   ei  = (const int*)d_in[1];
  const int*   bat = (const int*)d_in[2];
  const float* W1  = (const float*)d_in[3];  const float* bc1 = (const float*)d_in[4];
  const float* W2  = (const float*)d_in[5];  const float* bc2 = (const float*)d_in[6];
  const float* W3  = (const float*)d_in[7];  const float* bc3 = (const float*)d_in[8];
  const float* W4  = (const float*)d_in[9];  const float* bc4 = (const float*)d_in[10];
  const float* g1  = (const float*)d_in[11]; const float* bt1 = (const float*)d_in[12];
  const float* g2  = (const float*)d_in[13]; const float* bt2 = (const float*)d_in[14];
  const float* g3  = (const float*)d_in[15]; const float* bt3 = (const float*)d_in[16];

  const int N = in_sizes[0] / 3;
  const int E = in_sizes[1] / 2;
  const int NG = out_size / 128;  // out: [NG][128] f32, out_size in ELEMENTS
  const int* src = ei;
  const int* dst = ei + E;
  const size_t Epad = (size_t)E + (size_t)(ROWPAD - 1) * N + 64;

  float* base = (float*)d_ws;
  size_t o = 0;
  auto alloc = [&](size_t n) -> float* {
    float* p = base + o;
    o += (n + 63) & ~(size_t)63;
    return p;
  };
  // zeroed region (contiguous from d_ws start):
  float* bnacc  = alloc(3 * 128);  // per-layer [sum64][sumsq64]
  size_t zero_elems = o;
  // uninitialized (fully overwritten before read):
  int*   gstart = (int*)alloc(NG + 1);
  float* ppart  = alloc((size_t)NG * PM * 96);
  int2*  erec  = (int2*)alloc(2 * Epad);
  float* dinv  = alloc(N);
  int*   hist  = (int*)alloc(N);
  int*   offs  = (int*)alloc(N + 1);
  int*   bsum  = (int*)alloc(256);
  int*   bbase = (int*)alloc(257);
  int*   bcnt  = (int*)alloc(MAXB);
  int*   bbase2 = (int*)alloc(MAXB + 1);
  int*   bcur  = (int*)alloc(MAXB);
  float* ab    = alloc(128);
  float* bias2 = alloc(192);          // L2[64] L3[64] L4[32]
  u16*   wt2   = (u16*)alloc(8192);   // bf16 [4][64][64]
  u16*   wt3   = (u16*)alloc(8192);
  u16*   wt4   = (u16*)alloc(4096);   // bf16 [4][32][64]
  float* t1f   = alloc(3 * (size_t)N);
  float* t2f   = alloc(3 * (size_t)N);
  float* t3f   = alloc(3 * (size_t)N);
  u16*   T0    = (u16*)alloc((size_t)N * 32);  // bf16 [N][64]
  u16*   T1    = (u16*)alloc((size_t)N * 32);
  u16*   T2    = (u16*)alloc((size_t)N * 32);
  u16*   T3    = (u16*)alloc((size_t)N * 32);
  float* C32   = alloc((size_t)N * 32);

  hipMemsetAsync(d_ws, 0, zero_elems * sizeof(float), stream);

  const int NB = (N + 255) / 256;
  const int SB = (N + SC_CHUNK - 1) / SC_CHUNK;
  const int S  = (N + HSEG - 1) / HSEG;
  const int SP = S * HSEG;
  const int NBK = (N + 255) >> 8;
  unsigned* partial = (unsigned*)T0;  // alias
  int2* ebuck = (int2*)T2;            // alias

  k_wprep<<<64, 256, 0, stream>>>(W2, W3, W4, wt2, wt3, wt4);
  k_gbound<<<1, 128, 0, stream>>>(bat, gstart, N, NG);
  k_histseg<<<dim3(S, HC, 2), 256, 0, stream>>>(src, dst, partial, E, SP);
  k_histred<<<NB, 256, 0, stream>>>((const u8*)partial, dinv, hist, N, SP);
  k_scan1<<<SB, 256, 0, stream>>>(hist, bsum, N);
  k_scan2<<<1, 256, 0, stream>>>(bsum, bbase, SB);
  k_scan3<<<SB, 256, 0, stream>>>(hist, bbase, offs, N, SB);
  k_bcnt<<<NBK, 256, 0, stream>>>(hist, bcnt, N);
  k_bscan<<<1, 256, 0, stream>>>(bcnt, bbase2, bcur, NBK);
  k_part<<<512, 256, 0, stream>>>(src, dst, bcur, ebuck, E);
  k_place<<<NBK, 256, 0, stream>>>(ebuck, bbase2, offs, dinv, erec, N);

  const int PB64 = (N * 64 + 255) / 256;
  const int TB = (N + 63) / 64;
  const int NCB = TB < 512 ? TB : 512;  // combine grid: 2 blocks/CU, grid-stride over tiles
  const v4i* erec4 = (const v4i*)erec;

  // ---- layer 1: Fin=3 -> 64 (f32 props, merged combine w/ fused lrelu+BN stats) ----
  k_prop3<<<NB, 256, 0, stream>>>(x, nullptr, t1f, offs, erec4, N, 0);
  k_prop3<<<NB, 256, 0, stream>>>(t1f, x, t2f, offs, erec4, N, 1);
  k_prop3<<<NB, 256, 0, stream>>>(t2f, t1f, t3f, offs, erec4, N, 1);
  k_combine1<<<512, 256, 0, stream>>>(T0, x, t1f, t2f, t3f, W1, bc1, bnacc, N);
  k_bnfinal3<<<1, 256, 0, stream>>>(bnacc, g1, bt1, W2, bc2, ab, bias2, 1.0f / N, 64);

  // ---- layer 2 ----
  k_prop64b<1, 0, 0><<<PB64, 256, 0, stream>>>(T0, ab, nullptr, nullptr, T1, offs, erec4, N);
  k_prop64b<0, 1, 1><<<PB64, 256, 0, stream>>>(T1, nullptr, T0, ab, T2, offs, erec4, N);
  k_prop64b<0, 1, 0><<<PB64, 256, 0, stream>>>(T2, nullptr, T1, nullptr, T3, offs, erec4, N);
  k_combine_m<64, true, true><<<NCB, 256, 0, stream>>>(T0, T0, T1, T2, T3, wt2, ab, bias2,
                                                       bnacc + 128, N, TB);
  k_bnfinal3<<<1, 256, 0, stream>>>(bnacc + 128, g2, bt2, W3, bc3, ab, bias2 + 64, 1.0f / N, 64);

  // ---- layer 3 ----
  k_prop64b<1, 0, 0><<<PB64, 256, 0, stream>>>(T0, ab, nullptr, nullptr, T1, offs, erec4, N);
  k_prop64b<0, 1, 1><<<PB64, 256, 0, stream>>>(T1, nullptr, T0, ab, T2, offs, erec4, N);
  k_prop64b<0, 1, 0><<<PB64, 256, 0, stream>>>(T2, nullptr, T1, nullptr, T3, offs, erec4, N);
  k_combine_m<64, true, true><<<NCB, 256, 0, stream>>>(T0, T0, T1, T2, T3, wt3, ab, bias2 + 64,
                                                       bnacc + 256, N, TB);
  k_bnfinal3<<<1, 256, 0, stream>>>(bnacc + 256, g3, bt3, W4, bc4, ab, bias2 + 128, 1.0f / N, 32);

  // ---- layer 4: 64 -> 32 (f32 out C32) ----
  k_prop64b<1, 0, 0><<<PB64, 256, 0, stream>>>(T0, ab, nullptr, nullptr, T1, offs, erec4, N);
  k_prop64b<0, 1, 1><<<PB64, 256, 0, stream>>>(T1, nullptr, T0, ab, T2, offs, erec4, N);
  k_prop64b<0, 1, 0><<<PB64, 256, 0, stream>>>(T2, nullptr, T1, nullptr, T3, offs, erec4, N);
  k_combine_m<32, false, false><<<NCB, 256, 0, stream>>>(C32, T0, T1, T2, T3, wt4, ab, bias2 + 128,
                                                         nullptr, N, TB);

  // ---- pool (L2-normalize fused, atomic-free) ----
  k_pool3<<<NG * PM, 256, 0, stream>>>(C32, gstart, ppart);
  k_poolfin2<<<NG, 32, 0, stream>>>(ppart, gstart, (float*)d_out);
}

// Round 21
// 644.546 us; speedup vs baseline: 1.3136x; 1.0109x over previous
//
#include <hip/hip_runtime.h>

#define EPS_BN 1e-5f
#define ROWPAD 8    // CSR rows padded to multiple of 8 edges (src=0,w=0 filler)
#define HSEG 32768  // histogram bins per segment (packed u8 -> 32 KB LDS)
#define HC 64       // histogram edge-chunks
#define MAXB 512    // max dst-buckets (256 nodes each)
#define PM 24       // pooling chunks per graph (64*24=1536 blocks, ~6/CU)

typedef unsigned short u16;
typedef unsigned char u8;
typedef int v4i __attribute__((ext_vector_type(4)));
typedef short bf8v __attribute__((ext_vector_type(8)));   // 8 bf16 (4 VGPRs) MFMA A/B frag
typedef float f4v __attribute__((ext_vector_type(4)));    // MFMA C/D frag

__device__ __forceinline__ float b2f(u16 u) {
  return __uint_as_float(((unsigned)u) << 16);
}
__device__ __forceinline__ u16 f2b(float f) {  // RTNE
  unsigned u = __float_as_uint(f);
  u += 0x7fffu + ((u >> 16) & 1u);
  return (u16)(u >> 16);
}

// ---------------- preprocessing: packed-u8 LDS segmented histograms ----------------
// int4 vectorized edge loads (latency-bound fix): 8 edges in flight per thread.
__global__ void k_histseg(const int* __restrict__ src, const int* __restrict__ dst,
                          unsigned* __restrict__ partial, int E, int SP) {
  __shared__ unsigned bins[HSEG / 4];
  int s = blockIdx.x, c = blockIdx.y, z = blockIdx.z;
  int t = threadIdx.x;
  for (int i = t; i < HSEG / 4; i += 256) bins[i] = 0;
  __syncthreads();
  const int* keys = z ? dst : src;
  int lo = s * HSEG;

#define UPD(kk) { int k = (kk) - lo; \
    if ((unsigned)k < (unsigned)HSEG) atomicAdd(&bins[k >> 2], 1u << ((k & 3) * 8)); }

  if ((E & 3) == 0) {  // int4 path (dst = ei+E stays 16B-aligned)
    int E4 = E >> 2;
    int ck = (E4 + HC - 1) / HC;
    int i0 = c * ck, i1 = i0 + ck; if (i1 > E4) i1 = E4;
    const int4* k4 = (const int4*)keys;
    int i = i0 + t;
    for (; i + 256 < i1; i += 512) {
      int4 a = k4[i];
      int4 b = k4[i + 256];
      UPD(a.x); UPD(a.y); UPD(a.z); UPD(a.w);
      UPD(b.x); UPD(b.y); UPD(b.z); UPD(b.w);
    }
    if (i < i1) {
      int4 a = k4[i];
      UPD(a.x); UPD(a.y); UPD(a.z); UPD(a.w);
    }
  } else {  // scalar fallback
    int ck = (E + HC - 1) / HC;
    int e0 = c * ck, e1 = e0 + ck; if (e1 > E) e1 = E;
    for (int e = e0 + t; e < e1; e += 256) UPD(keys[e]);
  }
#undef UPD
  __syncthreads();
  unsigned* out = partial + (size_t)(z * HC + c) * (SP >> 2) + (lo >> 2);
  for (int i = t; i < HSEG / 4; i += 256) out[i] = bins[i];
}

__global__ void k_histred(const u8* __restrict__ partial, float* __restrict__ dinv,
                          int* __restrict__ hist, int N, int SP) {
  int n = blockIdx.x * 256 + threadIdx.x;
  if (n >= N) return;
  int a = 0, b = 0;
  for (int c = 0; c < HC; c++) a += partial[(size_t)c * SP + n];
  for (int c = 0; c < HC; c++) b += partial[(size_t)(HC + c) * SP + n];
  dinv[n] = a > 0 ? rsqrtf((float)a) : 0.f;
  hist[n] = b;
}

// ---- hierarchical scan over PADDED counts ----
#define SC_CHUNK 400

__device__ __forceinline__ int lds_incl_scan256(int* lds, int t, int v) {
  lds[t] = v; __syncthreads();
  for (int off = 1; off < 256; off <<= 1) {
    int u = (t >= off) ? lds[t - off] : 0;
    __syncthreads();
    lds[t] += u;
    __syncthreads();
  }
  return lds[t];
}

__device__ __forceinline__ int padcnt(int h) { return (h + (ROWPAD - 1)) & ~(ROWPAD - 1); }

__global__ void k_scan1(const int* __restrict__ hist, int* __restrict__ bsum, int N) {
  __shared__ int lds[256];
  int b = blockIdx.x, t = threadIdx.x;
  int lo = b * SC_CHUNK;
  int hi = lo + SC_CHUNK; if (hi > N) hi = N;
  int i0 = lo + t * 2;
  int s = 0;
  if (i0 < hi) s += padcnt(hist[i0]);
  if (i0 + 1 < hi) s += padcnt(hist[i0 + 1]);
  int incl = lds_incl_scan256(lds, t, s);
  if (t == 255) bsum[b] = incl;
}

__global__ void k_scan2(const int* __restrict__ bsum, int* __restrict__ bbase, int nb) {
  __shared__ int lds[256];
  int t = threadIdx.x;
  int v = (t < nb) ? bsum[t] : 0;
  int incl = lds_incl_scan256(lds, t, v);
  if (t < nb) bbase[t] = incl - v;
  if (t == nb - 1) bbase[nb] = incl;
}

__global__ void k_scan3(const int* __restrict__ hist, const int* __restrict__ bbase,
                        int* __restrict__ offs, int N, int nb) {
  __shared__ int lds[256];
  int b = blockIdx.x, t = threadIdx.x;
  int lo = b * SC_CHUNK;
  int hi = lo + SC_CHUNK; if (hi > N) hi = N;
  int i0 = lo + t * 2;
  int h0 = (i0 < hi) ? padcnt(hist[i0]) : 0;
  int h1 = (i0 + 1 < hi) ? padcnt(hist[i0 + 1]) : 0;
  int s = h0 + h1;
  int incl = lds_incl_scan256(lds, t, s);
  int run = bbase[b] + incl - s;
  if (i0 < hi) offs[i0] = run;
  if (i0 + 1 < hi) offs[i0 + 1] = run + h0;
  if (b == 0 && t == 0) offs[N] = bbase[nb];
}

// ---------------- two-phase binned scatter ----------------
__global__ void k_bcnt(const int* __restrict__ hist, int* __restrict__ bcnt, int N) {
  __shared__ int red[256];
  int b = blockIdx.x, t = threadIdx.x;
  int n = (b << 8) + t;
  red[t] = (n < N) ? hist[n] : 0;
  __syncthreads();
  for (int off = 128; off; off >>= 1) {
    if (t < off) red[t] += red[t + off];
    __syncthreads();
  }
  if (t == 0) bcnt[b] = red[0];
}

__global__ void k_bscan(const int* __restrict__ bcnt, int* __restrict__ bbase2,
                        int* __restrict__ bcur, int nb) {
  __shared__ int lds[256];
  int t = threadIdx.x;
  int i0 = 2 * t, i1 = 2 * t + 1;
  int v0 = (i0 < nb) ? bcnt[i0] : 0;
  int v1 = (i1 < nb) ? bcnt[i1] : 0;
  int s = v0 + v1;
  int incl = lds_incl_scan256(lds, t, s);
  int ex = incl - s;
  if (i0 < nb) { bbase2[i0] = ex; bcur[i0] = ex; }
  if (i1 < nb) { bbase2[i1] = ex + v0; bcur[i1] = ex + v0; }
  if (t == 255) bbase2[nb] = incl;
}

__global__ void k_part(const int* __restrict__ src, const int* __restrict__ dst,
                       int* __restrict__ bcur, int2* __restrict__ ebuck, int E) {
  __shared__ int lcnt[MAXB], lbase[MAXB];
  int t = threadIdx.x;
  for (int i = t; i < MAXB; i += 256) lcnt[i] = 0;
  __syncthreads();
  int ck = (E + gridDim.x - 1) / gridDim.x;
  int e0 = blockIdx.x * ck, e1 = e0 + ck; if (e1 > E) e1 = E;
  for (int e = e0 + t; e < e1; e += 256) atomicAdd(&lcnt[dst[e] >> 8], 1);
  __syncthreads();
  for (int i = t; i < MAXB; i += 256) {
    int c = lcnt[i];
    lbase[i] = c ? atomicAdd(&bcur[i], c) : 0;
    lcnt[i] = 0;
  }
  __syncthreads();
  for (int e = e0 + t; e < e1; e += 256) {
    int d = dst[e];
    int b = d >> 8;
    int ofs = atomicAdd(&lcnt[b], 1);
    int2 r; r.x = src[e]; r.y = d;
    ebuck[lbase[b] + ofs] = r;
  }
}

__global__ void k_place(const int2* __restrict__ ebuck, const int* __restrict__ bbase2,
                        const int* __restrict__ offs, const float* __restrict__ dinv,
                        int2* __restrict__ erec, int N) {
  __shared__ int lcur[256];
  int b = blockIdx.x, t = threadIdx.x;
  lcur[t] = 0;
  __syncthreads();
  int nlo = b << 8;
  int e0 = bbase2[b], e1 = bbase2[b + 1];
  for (int e = e0 + t; e < e1; e += 256) {
    int2 sd = ebuck[e];
    int s = sd.x, d = sd.y;
    int ofs = atomicAdd(&lcur[d - nlo], 1);
    int2 r;
    r.x = s;
    r.y = __float_as_int(-dinv[s] * dinv[d]);
    erec[offs[d] + ofs] = r;
  }
  __syncthreads();
  int n = nlo + t;
  if (n < N) {
    int st = offs[n] + lcur[t];
    int en = offs[n + 1];
    int2 z; z.x = 0; z.y = 0;
    for (int p = st; p < en; p++) erec[p] = z;
  }
}

// ---------------- propagation (padded CSR, bf16 features, scalar record loads) ----------------
// Template-specialized on (GAB, RECUR, OAB) [round 20, -13 us]: removes dead sw/branches
// on the 6-of-9 launches that never use them.
// 32-bit gather indexing [round 21]: (size_t)src*64+lane forced a 64-bit mul+carry chain
// per gather (compiler can't prove sext(x)*64 == sext(x*64)); node*64+lane < 2^23 at
// N=100K, so int (src<<6)+lane is exact -> one v_lshl_add_u32 + sgpr-base 32-bit-voffset
// load form. Identical addresses, bit-identical results.
template <int GAB, int RECUR, int OAB>
__global__ void k_prop64b(const u16* __restrict__ gf, const float* __restrict__ gab,
                          const u16* __restrict__ oldv, const float* __restrict__ oab,
                          u16* __restrict__ outv, const int* __restrict__ offs,
                          const v4i* __restrict__ erec4, int N) {
  int wid = (blockIdx.x * 256 + threadIdx.x) >> 6;
  int lane = threadIdx.x & 63;
  if (wid >= N) return;
  int row = __builtin_amdgcn_readfirstlane(wid);  // wave-uniform -> scalar loads for records
  int q = offs[row] >> 1, qe = offs[row + 1] >> 1;
  float acc = 0.f, sw = 0.f;
  for (; q + 8 <= qe; q += 8) {  // 16 records
    v4i m[8];
#pragma unroll
    for (int j = 0; j < 8; j++) m[j] = erec4[q + j];
    u16 g[16];
#pragma unroll
    for (int j = 0; j < 8; j++) {
      g[2 * j]     = gf[(m[j].x << 6) + lane];
      g[2 * j + 1] = gf[(m[j].z << 6) + lane];
    }
#pragma unroll
    for (int j = 0; j < 8; j++) {
      float w0 = __int_as_float(m[j].y), w1 = __int_as_float(m[j].w);
      acc += w0 * b2f(g[2 * j]) + w1 * b2f(g[2 * j + 1]);
      if (GAB) sw += w0 + w1;
    }
  }
  if (q < qe) {  // exactly 8 records
    v4i m[4];
#pragma unroll
    for (int j = 0; j < 4; j++) m[j] = erec4[q + j];
    u16 g[8];
#pragma unroll
    for (int j = 0; j < 4; j++) {
      g[2 * j]     = gf[(m[j].x << 6) + lane];
      g[2 * j + 1] = gf[(m[j].z << 6) + lane];
    }
#pragma unroll
    for (int j = 0; j < 4; j++) {
      float w0 = __int_as_float(m[j].y), w1 = __int_as_float(m[j].w);
      acc += w0 * b2f(g[2 * j]) + w1 * b2f(g[2 * j + 1]);
      if (GAB) sw += w0 + w1;
    }
  }
  float res = acc;
  if (GAB) res = gab[lane] * acc + gab[64 + lane] * sw;
  int idx = (wid << 6) + lane;
  if (RECUR) {
    float o = b2f(oldv[idx]);
    if (OAB) o = oab[lane] * o + oab[64 + lane];
    res = 2.f * res - o;
  }
  outv[idx] = f2b(res);
}

// F=3 f32 variant (layer 1)
__global__ void k_prop3(const float* __restrict__ gf, const float* __restrict__ oldv,
                        float* __restrict__ outv, const int* __restrict__ offs,
                        const v4i* __restrict__ erec4, int N, int recur) {
  int n = blockIdx.x * 256 + threadIdx.x;
  if (n >= N) return;
  int q = offs[n] >> 1, qe = offs[n + 1] >> 1;
  float a0 = 0.f, a1 = 0.f, a2 = 0.f;
  for (; q < qe; q += 4) {
    v4i m[4];
#pragma unroll
    for (int j = 0; j < 4; j++) m[j] = erec4[q + j];
#pragma unroll
    for (int j = 0; j < 4; j++) {
      float w0 = __int_as_float(m[j].y), w1 = __int_as_float(m[j].w);
      int s0 = m[j].x, s1 = m[j].z;
      a0 += w0 * gf[s0 * 3 + 0] + w1 * gf[s1 * 3 + 0];
      a1 += w0 * gf[s0 * 3 + 1] + w1 * gf[s1 * 3 + 1];
      a2 += w0 * gf[s0 * 3 + 2] + w1 * gf[s1 * 3 + 2];
    }
  }
  if (recur) {
    a0 = 2.f * a0 - oldv[n * 3 + 0];
    a1 = 2.f * a1 - oldv[n * 3 + 1];
    a2 = 2.f * a2 - oldv[n * 3 + 2];
  }
  outv[n * 3 + 0] = a0;
  outv[n * 3 + 1] = a1;
  outv[n * 3 + 2] = a2;
}

// ---------------- weight prep: f32 [4][64][FOUT] -> bf16 [4][FOUT][64] (transposed) ----------------
__global__ void k_wprep(const float* __restrict__ W2, const float* __restrict__ W3,
                        const float* __restrict__ W4, u16* __restrict__ WT2,
                        u16* __restrict__ WT3, u16* __restrict__ WT4) {
  int tid = blockIdx.x * 256 + threadIdx.x;
  if (tid < 16384) {
    int p = tid >> 12, j = (tid >> 6) & 63, k = tid & 63;
    WT2[tid] = f2b(W2[p * 4096 + k * 64 + j]);
    WT3[tid] = f2b(W3[p * 4096 + k * 64 + j]);
  }
  if (tid < 8192) {
    int p = tid >> 11, j = (tid >> 6) & 31, k = tid & 63;
    WT4[tid] = f2b(W4[p * 2048 + k * 32 + j]);
  }
}

// ---------------- MFMA combine: out = bias2 + sum_p Tp @ Wp  (K=256, bf16 MFMA) ----------------
// Weights-stationary: all B-fragments held in registers for the whole kernel
// (FOUT=64: 32 frags = 128 VGPRs). Each block grid-strides over 64-node tiles;
// inner loop = 8 coalesced 16B A-loads + 32 MFMAs, zero LDS traffic.
// BN sum/sumsq accumulate in registers across tiles; one LDS reduce + one
// atomicAdd pair per block at the end.
// A-frag: A[m=lane&15][k=quad*8+j] direct from T tables.
// B-frag: B[k][n=lane&15] from WT (bf16 [4][FOUT][64]); ab folded into p=0.
// C/D: col=lane&15, row=quad*4+reg.
template <int FOUT, bool OUTBF, bool DOBN>
__global__ __launch_bounds__(256, 2) void k_combine_m(
    void* __restrict__ outp, const u16* __restrict__ T0, const u16* __restrict__ T1,
    const u16* __restrict__ T2, const u16* __restrict__ T3, const u16* __restrict__ WTg,
    const float* __restrict__ ab, const float* __restrict__ bias2,
    float* __restrict__ gs, int N, int ntiles) {
  constexpr int NT = FOUT / 16;
  __shared__ float red[2 * FOUT * 16];
  int tid = threadIdx.x;
  int wv = tid >> 6, lane = tid & 63;
  int col = lane & 15, quad = lane >> 4;

  // ---- stage B into registers (weights-stationary), fold a[k] into p==0 ----
  bf8v B[4][2][NT];
#pragma unroll
  for (int p = 0; p < 4; p++) {
#pragma unroll
    for (int kb = 0; kb < 2; kb++) {
      f4v sc0, sc1;
      if (p == 0) {
        sc0 = *(const f4v*)(ab + kb * 32 + quad * 8);
        sc1 = *(const f4v*)(ab + kb * 32 + quad * 8 + 4);
      }
#pragma unroll
      for (int t = 0; t < NT; t++) {
        bf8v b = *(const bf8v*)(WTg + (size_t)(p * FOUT + t * 16 + col) * 64 + kb * 32 + quad * 8);
        if (p == 0) {
#pragma unroll
          for (int i = 0; i < 8; i++) {
            float sc = (i < 4) ? sc0[i] : sc1[i - 4];
            b[i] = (short)f2b(sc * b2f((u16)b[i]));
          }
        }
        B[p][kb][t] = b;
      }
    }
  }

  float bv[NT];
#pragma unroll
  for (int t = 0; t < NT; t++) bv[t] = bias2[t * 16 + col];

  float sum_[NT], sq_[NT];
#pragma unroll
  for (int t = 0; t < NT; t++) { sum_[t] = 0.f; sq_[t] = 0.f; }

  const u16* Tp[4] = {T0, T1, T2, T3};

  for (int tile = blockIdx.x; tile < ntiles; tile += gridDim.x) {
    int nb = tile * 64 + wv * 16;
    int node = nb + col;
    bool valid = node < N;

    bf8v A[4][2];
#pragma unroll
    for (int p = 0; p < 4; p++) {
#pragma unroll
      for (int kb = 0; kb < 2; kb++) {
        if (valid) {
          A[p][kb] = *(const bf8v*)(Tp[p] + (size_t)node * 64 + kb * 32 + quad * 8);
        } else {
#pragma unroll
          for (int i = 0; i < 8; i++) A[p][kb][i] = 0;
        }
      }
    }

    f4v acc[NT];
#pragma unroll
    for (int t = 0; t < NT; t++) {
      acc[t][0] = bv[t]; acc[t][1] = bv[t]; acc[t][2] = bv[t]; acc[t][3] = bv[t];
    }
#pragma unroll
    for (int p = 0; p < 4; p++)
#pragma unroll
      for (int kb = 0; kb < 2; kb++)
#pragma unroll
        for (int t = 0; t < NT; t++)
          acc[t] = __builtin_amdgcn_mfma_f32_16x16x32_bf16(A[p][kb], B[p][kb][t], acc[t], 0, 0, 0);

#pragma unroll
    for (int t = 0; t < NT; t++) {
#pragma unroll
      for (int r = 0; r < 4; r++) {
        int n2 = nb + quad * 4 + r;
        if (n2 < N) {
          float v = acc[t][r];
          if (DOBN) {
            v = v >= 0.f ? v : 0.01f * v;
            sum_[t] += v;
            sq_[t] += v * v;
          }
          int j = t * 16 + col;
          if (OUTBF) ((u16*)outp)[(size_t)n2 * FOUT + j] = f2b(v);
          else       ((float*)outp)[(size_t)n2 * FOUT + j] = v;
        }
      }
    }
  }

  if (DOBN) {
    float* redS = red;
    float* redQ = red + FOUT * 16;
#pragma unroll
    for (int t = 0; t < NT; t++) {
      redS[(t * 16 + col) * 16 + wv * 4 + quad] = sum_[t];
      redQ[(t * 16 + col) * 16 + wv * 4 + quad] = sq_[t];
    }
    __syncthreads();
    if (tid < FOUT) {
      float a_ = 0.f, b_ = 0.f;
      for (int w = 0; w < 16; w++) { a_ += redS[tid * 16 + w]; b_ += redQ[tid * 16 + w]; }
      atomicAdd(&gs[tid], a_);
      atomicAdd(&gs[64 + tid], b_);
    }
  }
}

// ---------------- merged layer-1 combine (Fin=3, f32 in, bf16 out) + FUSED lrelu/BN-stats ----
// Replaces combine1 + bnstats (saved a full 25.6 MB RW pass over T0).
// Grid-stride 512 blocks (4 waves x 1 node each/iter); stats in registers,
// one LDS reduce + one atomicAdd pair per block (k_combine_m DOBN pattern —
// NOT per-node atomics, which was the k_pool2 contention trap).
// Rounding pipeline bit-identical to old combine1+bnstats:
//   store f2b(acc) -> read b2f -> lrelu -> stats on f32 -> store f2b.
__global__ __launch_bounds__(256) void k_combine1(
    u16* __restrict__ H, const float* __restrict__ x,
    const float* __restrict__ t1, const float* __restrict__ t2,
    const float* __restrict__ t3, const float* __restrict__ W,
    const float* __restrict__ bias, float* __restrict__ gs, int N) {
  __shared__ float ws[768];  // [4][3][64]
  __shared__ float redS[4 * 64], redQ[4 * 64];
  int tid = threadIdx.x;
  for (int i = tid; i < 768; i += 256) ws[i] = W[i];
  int j = tid & 63, wv = tid >> 6;
  float bj = bias[j];
  float sum = 0.f, sq = 0.f;
  __syncthreads();
  const float* xs[4] = {x, t1, t2, t3};
  for (int n = blockIdx.x * 4 + wv; n < N; n += gridDim.x * 4) {
    float acc = bj;
#pragma unroll
    for (int p = 0; p < 4; p++)
#pragma unroll
      for (int i = 0; i < 3; i++)
        acc += xs[p][n * 3 + i] * ws[p * 192 + i * 64 + j];
    float v = b2f(f2b(acc));  // replicate old store-then-reload rounding
    v = v >= 0.f ? v : 0.01f * v;
    sum += v; sq += v * v;
    H[(size_t)n * 64 + j] = f2b(v);
  }
  redS[wv * 64 + j] = sum;
  redQ[wv * 64 + j] = sq;
  __syncthreads();
  if (tid < 64) {
    float a = redS[j] + redS[64 + j] + redS[128 + j] + redS[192 + j];
    float b = redQ[j] + redQ[64 + j] + redQ[128 + j] + redQ[192 + j];
    atomicAdd(&gs[j], a);
    atomicAdd(&gs[64 + j], b);
  }
}

// BN finalize + fold shift into next combine's bias.
// 256 threads (was 64 = ONE wave, 64 serial global loads -> 76 us cold in rocprof):
// k-loop split 4-way across waves (16 loads/thread), LDS reduce.
// ab = (a,b); bias2[j] = bias_next[j] + sum_k b[k] * Wnext0[k*FOUTN + j]
__global__ void k_bnfinal3(const float* __restrict__ gs, const float* __restrict__ g,
                           const float* __restrict__ bt, const float* __restrict__ Wn,
                           const float* __restrict__ bn, float* __restrict__ ab,
                           float* __restrict__ bias2, float Ninv, int FOUTN) {
  int t = threadIdx.x;  // 256
  __shared__ float bsh[64];
  __shared__ float part[4][64];
  if (t < 64) {
    float mu = gs[t] * Ninv;
    float var = gs[64 + t] * Ninv - mu * mu;
    float a = g[t] / sqrtf(var + EPS_BN);
    float b = bt[t] - mu * a;
    ab[t] = a;
    ab[64 + t] = b;
    bsh[t] = b;
  }
  __syncthreads();
  int kq = t >> 6, jl = t & 63;
  for (int j0 = 0; j0 < FOUTN; j0 += 64) {
    int j = j0 + jl;
    float s = 0.f;
    if (j < FOUTN) {
#pragma unroll
      for (int k = 0; k < 16; k++)
        s += bsh[kq * 16 + k] * Wn[(kq * 16 + k) * FOUTN + j];
    }
    part[kq][jl] = s;
    __syncthreads();
    if (kq == 0 && j < FOUTN)
      bias2[j] = bn[j] + part[0][jl] + part[1][jl] + part[2][jl] + part[3][jl];
    __syncthreads();
  }
}

// ---------------- pooling: atomic-free 3-stage (gbound -> chunk partials -> finalize) ----------------
// batch is sorted; 65 binary searches give graph row-ranges. Grid = NG*PM blocks,
// each owns graph g chunk c: register accumulate -> LDS reduce over 8 subgroups ->
// ONE non-atomic 96-float partial write. poolfin2 reduces PM partials per graph.
__global__ void k_gbound(const int* __restrict__ batch, int* __restrict__ gstart,
                         int N, int NG) {
  int g = blockIdx.x * blockDim.x + threadIdx.x;
  if (g > NG) return;
  int lo = 0, hi = N;
  while (lo < hi) {
    int mid = (lo + hi) >> 1;
    if (batch[mid] < g) lo = mid + 1; else hi = mid;
  }
  gstart[g] = lo;
}

__global__ void k_pool3(const float* __restrict__ H, const int* __restrict__ gstart,
                        float* __restrict__ ppart) {
  __shared__ float lsum[8][32], lmax[8][32], lmin[8][32];
  int f = threadIdx.x & 31;
  int sub = threadIdx.x >> 5;
  int g = blockIdx.x / PM, c = blockIdx.x % PM;
  int gs = gstart[g], ge = gstart[g + 1];
  int len = ge - gs;
  int lo = gs + (int)((long long)len * c / PM);
  int hi = gs + (int)((long long)len * (c + 1) / PM);
  float s = 0.f, mx = -3.4e38f, mn = 3.4e38f;
  for (int n = lo + sub; n < hi; n += 8) {
    float v = H[(size_t)n * 32 + f];
    float ss = v * v;
    for (int off = 16; off; off >>= 1) ss += __shfl_xor(ss, off, 32);
    v /= fmaxf(sqrtf(ss), 1e-12f);
    s += v; mx = fmaxf(mx, v); mn = fminf(mn, v);
  }
  lsum[sub][f] = s; lmax[sub][f] = mx; lmin[sub][f] = mn;
  __syncthreads();
  if (sub == 0) {
#pragma unroll
    for (int k = 1; k < 8; k++) {
      s += lsum[k][f];
      mx = fmaxf(mx, lmax[k][f]);
      mn = fminf(mn, lmin[k][f]);
    }
    float* slot = ppart + (size_t)blockIdx.x * 96;
    slot[f] = s; slot[32 + f] = mx; slot[64 + f] = mn;
  }
}

__global__ void k_poolfin2(const float* __restrict__ ppart, const int* __restrict__ gstart,
                           float* __restrict__ out) {
  int g = blockIdx.x, f = threadIdx.x;
  float s = 0.f, mx = -3.4e38f, mn = 3.4e38f;
  for (int c = 0; c < PM; c++) {
    const float* slot = ppart + (size_t)(g * PM + c) * 96;
    s += slot[f];
    mx = fmaxf(mx, slot[32 + f]);
    mn = fminf(mn, slot[64 + f]);
  }
  float cnt = (float)(gstart[g + 1] - gstart[g]);
  float c = fmaxf(cnt, 1.0f);
  out[g * 128 + f] = s / c;
  out[g * 128 + 32 + f] = mx;
  out[g * 128 + 64 + f] = mn;
  out[g * 128 + 96 + f] = s;
}

// ---------------- host ----------------

extern "C" void kernel_launch(void* const* d_in, const int* in_sizes, int n_in,
                              void* d_out, int out_size, void* d_ws, size_t ws_size,
                              hipStream_t stream) {
  const float* x   = (const float*)d_in[0];
  const int*   ei  = (const int*)d_in[1];
  const int*   bat = (const int*)d_in[2];
  const float* W1  = (const float*)d_in[3];  const float* bc1 = (const float*)d_in[4];
  const float* W2  = (const float*)d_in[5];  const float* bc2 = (const float*)d_in[6];
  const float* W3  = (const float*)d_in[7];  const float* bc3 = (const float*)d_in[8];
  const float* W4  = (const float*)d_in[9];  const float* bc4 = (const float*)d_in[10];
  const float* g1  = (const float*)d_in[11]; const float* bt1 = (const float*)d_in[12];
  const float* g2  = (const float*)d_in[13]; const float* bt2 = (const float*)d_in[14];
  const float* g3  = (const float*)d_in[15]; const float* bt3 = (const float*)d_in[16];

  const int N = in_sizes[0] / 3;
  const int E = in_sizes[1] / 2;
  const int NG = out_size / 128;  // out: [NG][128] f32, out_size in ELEMENTS
  const int* src = ei;
  const int* dst = ei + E;
  const size_t Epad = (size_t)E + (size_t)(ROWPAD - 1) * N + 64;

  float* base = (float*)d_ws;
  size_t o = 0;
  auto alloc = [&](size_t n) -> float* {
    float* p = base + o;
    o += (n + 63) & ~(size_t)63;
    return p;
  };
  // zeroed region (contiguous from d_ws start):
  float* bnacc  = alloc(3 * 128);  // per-layer [sum64][sumsq64]
  size_t zero_elems = o;
  // uninitialized (fully overwritten before read):
  int*   gstart = (int*)alloc(NG + 1);
  float* ppart  = alloc((size_t)NG * PM * 96);
  int2*  erec  = (int2*)alloc(2 * Epad);
  float* dinv  = alloc(N);
  int*   hist  = (int*)alloc(N);
  int*   offs  = (int*)alloc(N + 1);
  int*   bsum  = (int*)alloc(256);
  int*   bbase = (int*)alloc(257);
  int*   bcnt  = (int*)alloc(MAXB);
  int*   bbase2 = (int*)alloc(MAXB + 1);
  int*   bcur  = (int*)alloc(MAXB);
  float* ab    = alloc(128);
  float* bias2 = alloc(192);          // L2[64] L3[64] L4[32]
  u16*   wt2   = (u16*)alloc(8192);   // bf16 [4][64][64]
  u16*   wt3   = (u16*)alloc(8192);
  u16*   wt4   = (u16*)alloc(4096);   // bf16 [4][32][64]
  float* t1f   = alloc(3 * (size_t)N);
  float* t2f   = alloc(3 * (size_t)N);
  float* t3f   = alloc(3 * (size_t)N);
  u16*   T0    = (u16*)alloc((size_t)N * 32);  // bf16 [N][64]
  u16*   T1    = (u16*)alloc((size_t)N * 32);
  u16*   T2    = (u16*)alloc((size_t)N * 32);
  u16*   T3    = (u16*)alloc((size_t)N * 32);
  float* C32   = alloc((size_t)N * 32);

  hipMemsetAsync(d_ws, 0, zero_elems * sizeof(float), stream);

  const int NB = (N + 255) / 256;
  const int SB = (N + SC_CHUNK - 1) / SC_CHUNK;
  const int S  = (N + HSEG - 1) / HSEG;
  const int SP = S * HSEG;
  const int NBK = (N + 255) >> 8;
  unsigned* partial = (unsigned*)T0;  // alias
  int2* ebuck = (int2*)T2;            // alias

  k_wprep<<<64, 256, 0, stream>>>(W2, W3, W4, wt2, wt3, wt4);
  k_gbound<<<1, 128, 0, stream>>>(bat, gstart, N, NG);
  k_histseg<<<dim3(S, HC, 2), 256, 0, stream>>>(src, dst, partial, E, SP);
  k_histred<<<NB, 256, 0, stream>>>((const u8*)partial, dinv, hist, N, SP);
  k_scan1<<<SB, 256, 0, stream>>>(hist, bsum, N);
  k_scan2<<<1, 256, 0, stream>>>(bsum, bbase, SB);
  k_scan3<<<SB, 256, 0, stream>>>(hist, bbase, offs, N, SB);
  k_bcnt<<<NBK, 256, 0, stream>>>(hist, bcnt, N);
  k_bscan<<<1, 256, 0, stream>>>(bcnt, bbase2, bcur, NBK);
  k_part<<<512, 256, 0, stream>>>(src, dst, bcur, ebuck, E);
  k_place<<<NBK, 256, 0, stream>>>(ebuck, bbase2, offs, dinv, erec, N);

  const int PB64 = (N * 64 + 255) / 256;
  const int TB = (N + 63) / 64;
  const int NCB = TB < 512 ? TB : 512;  // combine grid: 2 blocks/CU, grid-stride over tiles
  const v4i* erec4 = (const v4i*)erec;

  // ---- layer 1: Fin=3 -> 64 (f32 props, merged combine w/ fused lrelu+BN stats) ----
  k_prop3<<<NB, 256, 0, stream>>>(x, nullptr, t1f, offs, erec4, N, 0);
  k_prop3<<<NB, 256, 0, stream>>>(t1f, x, t2f, offs, erec4, N, 1);
  k_prop3<<<NB, 256, 0, stream>>>(t2f, t1f, t3f, offs, erec4, N, 1);
  k_combine1<<<512, 256, 0, stream>>>(T0, x, t1f, t2f, t3f, W1, bc1, bnacc, N);
  k_bnfinal3<<<1, 256, 0, stream>>>(bnacc, g1, bt1, W2, bc2, ab, bias2, 1.0f / N, 64);

  // ---- layer 2 ----
  k_prop64b<1, 0, 0><<<PB64, 256, 0, stream>>>(T0, ab, nullptr, nullptr, T1, offs, erec4, N);
  k_prop64b<0, 1, 1><<<PB64, 256, 0, stream>>>(T1, nullptr, T0, ab, T2, offs, erec4, N);
  k_prop64b<0, 1, 0><<<PB64, 256, 0, stream>>>(T2, nullptr, T1, nullptr, T3, offs, erec4, N);
  k_combine_m<64, true, true><<<NCB, 256, 0, stream>>>(T0, T0, T1, T2, T3, wt2, ab, bias2,
                                                       bnacc + 128, N, TB);
  k_bnfinal3<<<1, 256, 0, stream>>>(bnacc + 128, g2, bt2, W3, bc3, ab, bias2 + 64, 1.0f / N, 64);

  // ---- layer 3 ----
  k_prop64b<1, 0, 0><<<PB64, 256, 0, stream>>>(T0, ab, nullptr, nullptr, T1, offs, erec4, N);
  k_prop64b<0, 1, 1><<<PB64, 256, 0, stream>>>(T1, nullptr, T0, ab, T2, offs, erec4, N);
  k_prop64b<0, 1, 0><<<PB64, 256, 0, stream>>>(T2, nullptr, T1, nullptr, T3, offs, erec4, N);
  k_combine_m<64, true, true><<<NCB, 256, 0, stream>>>(T0, T0, T1, T2, T3, wt3, ab, bias2 + 64,
                                                       bnacc + 256, N, TB);
  k_bnfinal3<<<1, 256, 0, stream>>>(bnacc + 256, g3, bt3, W4, bc4, ab, bias2 + 128, 1.0f / N, 32);

  // ---- layer 4: 64 -> 32 (f32 out C32) ----
  k_prop64b<1, 0, 0><<<PB64, 256, 0, stream>>>(T0, ab, nullptr, nullptr, T1, offs, erec4, N);
  k_prop64b<0, 1, 1><<<PB64, 256, 0, stream>>>(T1, nullptr, T0, ab, T2, offs, erec4, N);
  k_prop64b<0, 1, 0><<<PB64, 256, 0, stream>>>(T2, nullptr, T1, nullptr, T3, offs, erec4, N);
  k_combine_m<32, false, false><<<NCB, 256, 0, stream>>>(C32, T0, T1, T2, T3, wt4, ab, bias2 + 128,
                                                         nullptr, N, TB);

  // ---- pool (L2-normalize fused, atomic-free) ----
  k_pool3<<<NG * PM, 256, 0, stream>>>(C32, gstart, ppart);
  k_poolfin2<<<NG, 32, 0, stream>>>(ppart, gstart, (float*)d_out);
}

// Round 24
// 638.830 us; speedup vs baseline: 1.3253x; 1.0089x over previous
//
#include <hip/hip_runtime.h>

#define EPS_BN 1e-5f
#define ROWPAD 4    // CSR rows padded to multiple of 4 edges (src=0,w=0 filler; was 8 ->
                    // ~18% fake gathers at avg deg 16, now ~9%; w=0 keeps sums identical)
#define HSEG 32768  // histogram bins per segment (packed u8 -> 32 KB LDS)
#define HC 64       // histogram edge-chunks
#define MAXB 512    // max dst-buckets (256 nodes each)
#define PM 24       // pooling chunks per graph (64*24=1536 blocks, ~6/CU)

typedef unsigned short u16;
typedef unsigned char u8;
typedef int v4i __attribute__((ext_vector_type(4)));
typedef short bf8v __attribute__((ext_vector_type(8)));   // 8 bf16 (4 VGPRs) MFMA A/B frag
typedef float f4v __attribute__((ext_vector_type(4)));    // MFMA C/D frag

__device__ __forceinline__ float b2f(u16 u) {
  return __uint_as_float(((unsigned)u) << 16);
}
__device__ __forceinline__ u16 f2b(float f) {  // RTNE
  unsigned u = __float_as_uint(f);
  u += 0x7fffu + ((u >> 16) & 1u);
  return (u16)(u >> 16);
}

// ---------------- preprocessing: packed-u8 LDS segmented histograms ----------------
// int4 vectorized edge loads (latency-bound fix): 8 edges in flight per thread.
__global__ void k_histseg(const int* __restrict__ src, const int* __restrict__ dst,
                          unsigned* __restrict__ partial, int E, int SP) {
  __shared__ unsigned bins[HSEG / 4];
  int s = blockIdx.x, c = blockIdx.y, z = blockIdx.z;
  int t = threadIdx.x;
  for (int i = t; i < HSEG / 4; i += 256) bins[i] = 0;
  __syncthreads();
  const int* keys = z ? dst : src;
  int lo = s * HSEG;

#define UPD(kk) { int k = (kk) - lo; \
    if ((unsigned)k < (unsigned)HSEG) atomicAdd(&bins[k >> 2], 1u << ((k & 3) * 8)); }

  if ((E & 3) == 0) {  // int4 path (dst = ei+E stays 16B-aligned)
    int E4 = E >> 2;
    int ck = (E4 + HC - 1) / HC;
    int i0 = c * ck, i1 = i0 + ck; if (i1 > E4) i1 = E4;
    const int4* k4 = (const int4*)keys;
    int i = i0 + t;
    for (; i + 256 < i1; i += 512) {
      int4 a = k4[i];
      int4 b = k4[i + 256];
      UPD(a.x); UPD(a.y); UPD(a.z); UPD(a.w);
      UPD(b.x); UPD(b.y); UPD(b.z); UPD(b.w);
    }
    if (i < i1) {
      int4 a = k4[i];
      UPD(a.x); UPD(a.y); UPD(a.z); UPD(a.w);
    }
  } else {  // scalar fallback
    int ck = (E + HC - 1) / HC;
    int e0 = c * ck, e1 = e0 + ck; if (e1 > E) e1 = E;
    for (int e = e0 + t; e < e1; e += 256) UPD(keys[e]);
  }
#undef UPD
  __syncthreads();
  unsigned* out = partial + (size_t)(z * HC + c) * (SP >> 2) + (lo >> 2);
  for (int i = t; i < HSEG / 4; i += 256) out[i] = bins[i];
}

__global__ void k_histred(const u8* __restrict__ partial, float* __restrict__ dinv,
                          int* __restrict__ hist, int N, int SP) {
  int n = blockIdx.x * 256 + threadIdx.x;
  if (n >= N) return;
  int a = 0, b = 0;
  for (int c = 0; c < HC; c++) a += partial[(size_t)c * SP + n];
  for (int c = 0; c < HC; c++) b += partial[(size_t)(HC + c) * SP + n];
  dinv[n] = a > 0 ? rsqrtf((float)a) : 0.f;
  hist[n] = b;
}

// ---- hierarchical scan over PADDED counts ----
#define SC_CHUNK 400

__device__ __forceinline__ int lds_incl_scan256(int* lds, int t, int v) {
  lds[t] = v; __syncthreads();
  for (int off = 1; off < 256; off <<= 1) {
    int u = (t >= off) ? lds[t - off] : 0;
    __syncthreads();
    lds[t] += u;
    __syncthreads();
  }
  return lds[t];
}

__device__ __forceinline__ int padcnt(int h) { return (h + (ROWPAD - 1)) & ~(ROWPAD - 1); }

__global__ void k_scan1(const int* __restrict__ hist, int* __restrict__ bsum, int N) {
  __shared__ int lds[256];
  int b = blockIdx.x, t = threadIdx.x;
  int lo = b * SC_CHUNK;
  int hi = lo + SC_CHUNK; if (hi > N) hi = N;
  int i0 = lo + t * 2;
  int s = 0;
  if (i0 < hi) s += padcnt(hist[i0]);
  if (i0 + 1 < hi) s += padcnt(hist[i0 + 1]);
  int incl = lds_incl_scan256(lds, t, s);
  if (t == 255) bsum[b] = incl;
}

__global__ void k_scan2(const int* __restrict__ bsum, int* __restrict__ bbase, int nb) {
  __shared__ int lds[256];
  int t = threadIdx.x;
  int v = (t < nb) ? bsum[t] : 0;
  int incl = lds_incl_scan256(lds, t, v);
  if (t < nb) bbase[t] = incl - v;
  if (t == nb - 1) bbase[nb] = incl;
}

__global__ void k_scan3(const int* __restrict__ hist, const int* __restrict__ bbase,
                        int* __restrict__ offs, int N, int nb) {
  __shared__ int lds[256];
  int b = blockIdx.x, t = threadIdx.x;
  int lo = b * SC_CHUNK;
  int hi = lo + SC_CHUNK; if (hi > N) hi = N;
  int i0 = lo + t * 2;
  int h0 = (i0 < hi) ? padcnt(hist[i0]) : 0;
  int h1 = (i0 + 1 < hi) ? padcnt(hist[i0 + 1]) : 0;
  int s = h0 + h1;
  int incl = lds_incl_scan256(lds, t, s);
  int run = bbase[b] + incl - s;
  if (i0 < hi) offs[i0] = run;
  if (i0 + 1 < hi) offs[i0 + 1] = run + h0;
  if (b == 0 && t == 0) offs[N] = bbase[nb];
}

// ---------------- two-phase binned scatter ----------------
__global__ void k_bcnt(const int* __restrict__ hist, int* __restrict__ bcnt, int N) {
  __shared__ int red[256];
  int b = blockIdx.x, t = threadIdx.x;
  int n = (b << 8) + t;
  red[t] = (n < N) ? hist[n] : 0;
  __syncthreads();
  for (int off = 128; off; off >>= 1) {
    if (t < off) red[t] += red[t + off];
    __syncthreads();
  }
  if (t == 0) bcnt[b] = red[0];
}

__global__ void k_bscan(const int* __restrict__ bcnt, int* __restrict__ bbase2,
                        int* __restrict__ bcur, int nb) {
  __shared__ int lds[256];
  int t = threadIdx.x;
  int i0 = 2 * t, i1 = 2 * t + 1;
  int v0 = (i0 < nb) ? bcnt[i0] : 0;
  int v1 = (i1 < nb) ? bcnt[i1] : 0;
  int s = v0 + v1;
  int incl = lds_incl_scan256(lds, t, s);
  int ex = incl - s;
  if (i0 < nb) { bbase2[i0] = ex; bcur[i0] = ex; }
  if (i1 < nb) { bbase2[i1] = ex + v0; bcur[i1] = ex + v0; }
  if (t == 255) bbase2[nb] = incl;
}

__global__ void k_part(const int* __restrict__ src, const int* __restrict__ dst,
                       int* __restrict__ bcur, int2* __restrict__ ebuck, int E) {
  __shared__ int lcnt[MAXB], lbase[MAXB];
  int t = threadIdx.x;
  for (int i = t; i < MAXB; i += 256) lcnt[i] = 0;
  __syncthreads();
  int ck = (E + gridDim.x - 1) / gridDim.x;
  int e0 = blockIdx.x * ck, e1 = e0 + ck; if (e1 > E) e1 = E;
  for (int e = e0 + t; e < e1; e += 256) atomicAdd(&lcnt[dst[e] >> 8], 1);
  __syncthreads();
  for (int i = t; i < MAXB; i += 256) {
    int c = lcnt[i];
    lbase[i] = c ? atomicAdd(&bcur[i], c) : 0;
    lcnt[i] = 0;
  }
  __syncthreads();
  for (int e = e0 + t; e < e1; e += 256) {
    int d = dst[e];
    int b = d >> 8;
    int ofs = atomicAdd(&lcnt[b], 1);
    int2 r; r.x = src[e]; r.y = d;
    ebuck[lbase[b] + ofs] = r;
  }
}

__global__ void k_place(const int2* __restrict__ ebuck, const int* __restrict__ bbase2,
                        const int* __restrict__ offs, const float* __restrict__ dinv,
                        int2* __restrict__ erec, int N) {
  __shared__ int lcur[256];
  int b = blockIdx.x, t = threadIdx.x;
  lcur[t] = 0;
  __syncthreads();
  int nlo = b << 8;
  int e0 = bbase2[b], e1 = bbase2[b + 1];
  for (int e = e0 + t; e < e1; e += 256) {
    int2 sd = ebuck[e];
    int s = sd.x, d = sd.y;
    int ofs = atomicAdd(&lcur[d - nlo], 1);
    int2 r;
    r.x = s;
    r.y = __float_as_int(-dinv[s] * dinv[d]);
    erec[offs[d] + ofs] = r;
  }
  __syncthreads();
  int n = nlo + t;
  if (n < N) {
    int st = offs[n] + lcur[t];
    int en = offs[n + 1];
    int2 z; z.x = 0; z.y = 0;
    for (int p = st; p < en; p++) erec[p] = z;
  }
}

// ---------------- propagation (padded CSR, bf16 features, scalar record loads) ----------------
// Template-specialized on (GAB, RECUR, OAB) [round 20, -13 us] + 32-bit gather indexing
// [round 21, -7 us]. ROWPAD 8->4 [round 22]: tails now cover remainders {0,2,4,6} records
// via one 4-record block + one 2-record block; fillers have w=0 so sums are unchanged.
template <int GAB, int RECUR, int OAB>
__global__ void k_prop64b(const u16* __restrict__ gf, const float* __restrict__ gab,
                          const u16* __restrict__ oldv, const float* __restrict__ oab,
                          u16* __restrict__ outv, const int* __restrict__ offs,
                          const v4i* __restrict__ erec4, int N) {
  int wid = (blockIdx.x * 256 + threadIdx.x) >> 6;
  int lane = threadIdx.x & 63;
  if (wid >= N) return;
  int row = __builtin_amdgcn_readfirstlane(wid);  // wave-uniform -> scalar loads for records
  int q = offs[row] >> 1, qe = offs[row + 1] >> 1;
  float acc = 0.f, sw = 0.f;
  for (; q + 8 <= qe; q += 8) {  // 16 records
    v4i m[8];
#pragma unroll
    for (int j = 0; j < 8; j++) m[j] = erec4[q + j];
    u16 g[16];
#pragma unroll
    for (int j = 0; j < 8; j++) {
      g[2 * j]     = gf[(m[j].x << 6) + lane];
      g[2 * j + 1] = gf[(m[j].z << 6) + lane];
    }
#pragma unroll
    for (int j = 0; j < 8; j++) {
      float w0 = __int_as_float(m[j].y), w1 = __int_as_float(m[j].w);
      acc += w0 * b2f(g[2 * j]) + w1 * b2f(g[2 * j + 1]);
      if (GAB) sw += w0 + w1;
    }
  }
  if (q + 4 <= qe) {  // 8 edges (4 records)
    v4i m[4];
#pragma unroll
    for (int j = 0; j < 4; j++) m[j] = erec4[q + j];
    u16 g[8];
#pragma unroll
    for (int j = 0; j < 4; j++) {
      g[2 * j]     = gf[(m[j].x << 6) + lane];
      g[2 * j + 1] = gf[(m[j].z << 6) + lane];
    }
#pragma unroll
    for (int j = 0; j < 4; j++) {
      float w0 = __int_as_float(m[j].y), w1 = __int_as_float(m[j].w);
      acc += w0 * b2f(g[2 * j]) + w1 * b2f(g[2 * j + 1]);
      if (GAB) sw += w0 + w1;
    }
    q += 4;
  }
  if (q < qe) {  // 4 edges (2 records)
    v4i m[2];
#pragma unroll
    for (int j = 0; j < 2; j++) m[j] = erec4[q + j];
    u16 g[4];
#pragma unroll
    for (int j = 0; j < 2; j++) {
      g[2 * j]     = gf[(m[j].x << 6) + lane];
      g[2 * j + 1] = gf[(m[j].z << 6) + lane];
    }
#pragma unroll
    for (int j = 0; j < 2; j++) {
      float w0 = __int_as_float(m[j].y), w1 = __int_as_float(m[j].w);
      acc += w0 * b2f(g[2 * j]) + w1 * b2f(g[2 * j + 1]);
      if (GAB) sw += w0 + w1;
    }
  }
  float res = acc;
  if (GAB) res = gab[lane] * acc + gab[64 + lane] * sw;
  int idx = (wid << 6) + lane;
  if (RECUR) {
    float o = b2f(oldv[idx]);
    if (OAB) o = oab[lane] * o + oab[64 + lane];
    res = 2.f * res - o;
  }
  outv[idx] = f2b(res);
}

// F=3 f32 variant (layer 1): 4-record main loop + 2-record tail (ROWPAD=4)
__global__ void k_prop3(const float* __restrict__ gf, const float* __restrict__ oldv,
                        float* __restrict__ outv, const int* __restrict__ offs,
                        const v4i* __restrict__ erec4, int N, int recur) {
  int n = blockIdx.x * 256 + threadIdx.x;
  if (n >= N) return;
  int q = offs[n] >> 1, qe = offs[n + 1] >> 1;
  float a0 = 0.f, a1 = 0.f, a2 = 0.f;
  for (; q + 4 <= qe; q += 4) {
    v4i m[4];
#pragma unroll
    for (int j = 0; j < 4; j++) m[j] = erec4[q + j];
#pragma unroll
    for (int j = 0; j < 4; j++) {
      float w0 = __int_as_float(m[j].y), w1 = __int_as_float(m[j].w);
      int s0 = m[j].x, s1 = m[j].z;
      a0 += w0 * gf[s0 * 3 + 0] + w1 * gf[s1 * 3 + 0];
      a1 += w0 * gf[s0 * 3 + 1] + w1 * gf[s1 * 3 + 1];
      a2 += w0 * gf[s0 * 3 + 2] + w1 * gf[s1 * 3 + 2];
    }
  }
  if (q < qe) {  // 2 records
    v4i m[2];
#pragma unroll
    for (int j = 0; j < 2; j++) m[j] = erec4[q + j];
#pragma unroll
    for (int j = 0; j < 2; j++) {
      float w0 = __int_as_float(m[j].y), w1 = __int_as_float(m[j].w);
      int s0 = m[j].x, s1 = m[j].z;
      a0 += w0 * gf[s0 * 3 + 0] + w1 * gf[s1 * 3 + 0];
      a1 += w0 * gf[s0 * 3 + 1] + w1 * gf[s1 * 3 + 1];
      a2 += w0 * gf[s0 * 3 + 2] + w1 * gf[s1 * 3 + 2];
    }
  }
  if (recur) {
    a0 = 2.f * a0 - oldv[n * 3 + 0];
    a1 = 2.f * a1 - oldv[n * 3 + 1];
    a2 = 2.f * a2 - oldv[n * 3 + 2];
  }
  outv[n * 3 + 0] = a0;
  outv[n * 3 + 1] = a1;
  outv[n * 3 + 2] = a2;
}

// ---------------- weight prep: f32 [4][64][FOUT] -> bf16 [4][FOUT][64] (transposed) ----------------
__global__ void k_wprep(const float* __restrict__ W2, const float* __restrict__ W3,
                        const float* __restrict__ W4, u16* __restrict__ WT2,
                        u16* __restrict__ WT3, u16* __restrict__ WT4) {
  int tid = blockIdx.x * 256 + threadIdx.x;
  if (tid < 16384) {
    int p = tid >> 12, j = (tid >> 6) & 63, k = tid & 63;
    WT2[tid] = f2b(W2[p * 4096 + k * 64 + j]);
    WT3[tid] = f2b(W3[p * 4096 + k * 64 + j]);
  }
  if (tid < 8192) {
    int p = tid >> 11, j = (tid >> 6) & 31, k = tid & 63;
    WT4[tid] = f2b(W4[p * 2048 + k * 32 + j]);
  }
}

// ---------------- MFMA combine: out = bias2 + sum_p Tp @ Wp  (K=256, bf16 MFMA) ----------------
// Weights-stationary: all B-fragments held in registers for the whole kernel
// (FOUT=64: 32 frags = 128 VGPRs). Each block grid-strides over 64-node tiles;
// inner loop = 8 coalesced 16B A-loads + 32 MFMAs, zero LDS traffic.
// BN sum/sumsq accumulate in registers across tiles; one LDS reduce + one
// atomicAdd pair per block at the end.
// A-frag: A[m=lane&15][k=quad*8+j] direct from T tables.
// B-frag: B[k][n=lane&15] from WT (bf16 [4][FOUT][64]); ab folded into p=0.
// C/D: col=lane&15, row=quad*4+reg.
template <int FOUT, bool OUTBF, bool DOBN>
__global__ __launch_bounds__(256, 2) void k_combine_m(
    void* __restrict__ outp, const u16* __restrict__ T0, const u16* __restrict__ T1,
    const u16* __restrict__ T2, const u16* __restrict__ T3, const u16* __restrict__ WTg,
    const float* __restrict__ ab, const float* __restrict__ bias2,
    float* __restrict__ gs, int N, int ntiles) {
  constexpr int NT = FOUT / 16;
  __shared__ float red[2 * FOUT * 16];
  int tid = threadIdx.x;
  int wv = tid >> 6, lane = tid & 63;
  int col = lane & 15, quad = lane >> 4;

  // ---- stage B into registers (weights-stationary), fold a[k] into p==0 ----
  bf8v B[4][2][NT];
#pragma unroll
  for (int p = 0; p < 4; p++) {
#pragma unroll
    for (int kb = 0; kb < 2; kb++) {
      f4v sc0, sc1;
      if (p == 0) {
        sc0 = *(const f4v*)(ab + kb * 32 + quad * 8);
        sc1 = *(const f4v*)(ab + kb * 32 + quad * 8 + 4);
      }
#pragma unroll
      for (int t = 0; t < NT; t++) {
        bf8v b = *(const bf8v*)(WTg + (size_t)(p * FOUT + t * 16 + col) * 64 + kb * 32 + quad * 8);
        if (p == 0) {
#pragma unroll
          for (int i = 0; i < 8; i++) {
            float sc = (i < 4) ? sc0[i] : sc1[i - 4];
            b[i] = (short)f2b(sc * b2f((u16)b[i]));
          }
        }
        B[p][kb][t] = b;
      }
    }
  }

  float bv[NT];
#pragma unroll
  for (int t = 0; t < NT; t++) bv[t] = bias2[t * 16 + col];

  float sum_[NT], sq_[NT];
#pragma unroll
  for (int t = 0; t < NT; t++) { sum_[t] = 0.f; sq_[t] = 0.f; }

  const u16* Tp[4] = {T0, T1, T2, T3};

  for (int tile = blockIdx.x; tile < ntiles; tile += gridDim.x) {
    int nb = tile * 64 + wv * 16;
    int node = nb + col;
    bool valid = node < N;

    bf8v A[4][2];
#pragma unroll
    for (int p = 0; p < 4; p++) {
#pragma unroll
      for (int kb = 0; kb < 2; kb++) {
        if (valid) {
          A[p][kb] = *(const bf8v*)(Tp[p] + (size_t)node * 64 + kb * 32 + quad * 8);
        } else {
#pragma unroll
          for (int i = 0; i < 8; i++) A[p][kb][i] = 0;
        }
      }
    }

    f4v acc[NT];
#pragma unroll
    for (int t = 0; t < NT; t++) {
      acc[t][0] = bv[t]; acc[t][1] = bv[t]; acc[t][2] = bv[t]; acc[t][3] = bv[t];
    }
#pragma unroll
    for (int p = 0; p < 4; p++)
#pragma unroll
      for (int kb = 0; kb < 2; kb++)
#pragma unroll
        for (int t = 0; t < NT; t++)
          acc[t] = __builtin_amdgcn_mfma_f32_16x16x32_bf16(A[p][kb], B[p][kb][t], acc[t], 0, 0, 0);

#pragma unroll
    for (int t = 0; t < NT; t++) {
#pragma unroll
      for (int r = 0; r < 4; r++) {
        int n2 = nb + quad * 4 + r;
        if (n2 < N) {
          float v = acc[t][r];
          if (DOBN) {
            v = v >= 0.f ? v : 0.01f * v;
            sum_[t] += v;
            sq_[t] += v * v;
          }
          int j = t * 16 + col;
          if (OUTBF) ((u16*)outp)[(size_t)n2 * FOUT + j] = f2b(v);
          else       ((float*)outp)[(size_t)n2 * FOUT + j] = v;
        }
      }
    }
  }

  if (DOBN) {
    float* redS = red;
    float* redQ = red + FOUT * 16;
#pragma unroll
    for (int t = 0; t < NT; t++) {
      redS[(t * 16 + col) * 16 + wv * 4 + quad] = sum_[t];
      redQ[(t * 16 + col) * 16 + wv * 4 + quad] = sq_[t];
    }
    __syncthreads();
    if (tid < FOUT) {
      float a_ = 0.f, b_ = 0.f;
      for (int w = 0; w < 16; w++) { a_ += redS[tid * 16 + w]; b_ += redQ[tid * 16 + w]; }
      atomicAdd(&gs[tid], a_);
      atomicAdd(&gs[64 + tid], b_);
    }
  }
}

// ---------------- merged layer-1 combine (Fin=3, f32 in, bf16 out) + FUSED lrelu/BN-stats ----
// Replaces combine1 + bnstats (saved a full 25.6 MB RW pass over T0).
// Grid-stride 512 blocks (4 waves x 1 node each/iter); stats in registers,
// one LDS reduce + one atomicAdd pair per block (k_combine_m DOBN pattern —
// NOT per-node atomics, which was the k_pool2 contention trap).
// Rounding pipeline bit-identical to old combine1+bnstats:
//   store f2b(acc) -> read b2f -> lrelu -> stats on f32 -> store f2b.
__global__ __launch_bounds__(256) void k_combine1(
    u16* __restrict__ H, const float* __restrict__ x,
    const float* __restrict__ t1, const float* __restrict__ t2,
    const float* __restrict__ t3, const float* __restrict__ W,
    const float* __restrict__ bias, float* __restrict__ gs, int N) {
  __shared__ float ws[768];  // [4][3][64]
  __shared__ float redS[4 * 64], redQ[4 * 64];
  int tid = threadIdx.x;
  for (int i = tid; i < 768; i += 256) ws[i] = W[i];
  int j = tid & 63, wv = tid >> 6;
  float bj = bias[j];
  float sum = 0.f, sq = 0.f;
  __syncthreads();
  const float* xs[4] = {x, t1, t2, t3};
  for (int n = blockIdx.x * 4 + wv; n < N; n += gridDim.x * 4) {
    float acc = bj;
#pragma unroll
    for (int p = 0; p < 4; p++)
#pragma unroll
      for (int i = 0; i < 3; i++)
        acc += xs[p][n * 3 + i] * ws[p * 192 + i * 64 + j];
    float v = b2f(f2b(acc));  // replicate old store-then-reload rounding
    v = v >= 0.f ? v : 0.01f * v;
    sum += v; sq += v * v;
    H[(size_t)n * 64 + j] = f2b(v);
  }
  redS[wv * 64 + j] = sum;
  redQ[wv * 64 + j] = sq;
  __syncthreads();
  if (tid < 64) {
    float a = redS[j] + redS[64 + j] + redS[128 + j] + redS[192 + j];
    float b = redQ[j] + redQ[64 + j] + redQ[128 + j] + redQ[192 + j];
    atomicAdd(&gs[j], a);
    atomicAdd(&gs[64 + j], b);
  }
}

// BN finalize + fold shift into next combine's bias.
// 256 threads (was 64 = ONE wave, 64 serial global loads -> 76 us cold in rocprof):
// k-loop split 4-way across waves (16 loads/thread), LDS reduce.
// ab = (a,b); bias2[j] = bias_next[j] + sum_k b[k] * Wnext0[k*FOUTN + j]
__global__ void k_bnfinal3(const float* __restrict__ gs, const float* __restrict__ g,
                           const float* __restrict__ bt, const float* __restrict__ Wn,
                           const float* __restrict__ bn, float* __restrict__ ab,
                           float* __restrict__ bias2, float Ninv, int FOUTN) {
  int t = threadIdx.x;  // 256
  __shared__ float bsh[64];
  __shared__ float part[4][64];
  if (t < 64) {
    float mu = gs[t] * Ninv;
    float var = gs[64 + t] * Ninv - mu * mu;
    float a = g[t] / sqrtf(var + EPS_BN);
    float b = bt[t] - mu * a;
    ab[t] = a;
    ab[64 + t] = b;
    bsh[t] = b;
  }
  __syncthreads();
  int kq = t >> 6, jl = t & 63;
  for (int j0 = 0; j0 < FOUTN; j0 += 64) {
    int j = j0 + jl;
    float s = 0.f;
    if (j < FOUTN) {
#pragma unroll
      for (int k = 0; k < 16; k++)
        s += bsh[kq * 16 + k] * Wn[(kq * 16 + k) * FOUTN + j];
    }
    part[kq][jl] = s;
    __syncthreads();
    if (kq == 0 && j < FOUTN)
      bias2[j] = bn[j] + part[0][jl] + part[1][jl] + part[2][jl] + part[3][jl];
    __syncthreads();
  }
}

// ---------------- pooling: atomic-free 3-stage (gbound -> chunk partials -> finalize) ----------------
// batch is sorted; 65 binary searches give graph row-ranges. Grid = NG*PM blocks,
// each owns graph g chunk c: register accumulate -> LDS reduce over 8 subgroups ->
// ONE non-atomic 96-float partial write. poolfin2 reduces PM partials per graph.
__global__ void k_gbound(const int* __restrict__ batch, int* __restrict__ gstart,
                         int N, int NG) {
  int g = blockIdx.x * blockDim.x + threadIdx.x;
  if (g > NG) return;
  int lo = 0, hi = N;
  while (lo < hi) {
    int mid = (lo + hi) >> 1;
    if (batch[mid] < g) lo = mid + 1; else hi = mid;
  }
  gstart[g] = lo;
}

__global__ void k_pool3(const float* __restrict__ H, const int* __restrict__ gstart,
                        float* __restrict__ ppart) {
  __shared__ float lsum[8][32], lmax[8][32], lmin[8][32];
  int f = threadIdx.x & 31;
  int sub = threadIdx.x >> 5;
  int g = blockIdx.x / PM, c = blockIdx.x % PM;
  int gs = gstart[g], ge = gstart[g + 1];
  int len = ge - gs;
  int lo = gs + (int)((long long)len * c / PM);
  int hi = gs + (int)((long long)len * (c + 1) / PM);
  float s = 0.f, mx = -3.4e38f, mn = 3.4e38f;
  for (int n = lo + sub; n < hi; n += 8) {
    float v = H[(size_t)n * 32 + f];
    float ss = v * v;
    for (int off = 16; off; off >>= 1) ss += __shfl_xor(ss, off, 32);
    v /= fmaxf(sqrtf(ss), 1e-12f);
    s += v; mx = fmaxf(mx, v); mn = fminf(mn, v);
  }
  lsum[sub][f] = s; lmax[sub][f] = mx; lmin[sub][f] = mn;
  __syncthreads();
  if (sub == 0) {
#pragma unroll
    for (int k = 1; k < 8; k++) {
      s += lsum[k][f];
      mx = fmaxf(mx, lmax[k][f]);
      mn = fminf(mn, lmin[k][f]);
    }
    float* slot = ppart + (size_t)blockIdx.x * 96;
    slot[f] = s; slot[32 + f] = mx; slot[64 + f] = mn;
  }
}

__global__ void k_poolfin2(const float* __restrict__ ppart, const int* __restrict__ gstart,
                           float* __restrict__ out) {
  int g = blockIdx.x, f = threadIdx.x;
  float s = 0.f, mx = -3.4e38f, mn = 3.4e38f;
  for (int c = 0; c < PM; c++) {
    const float* slot = ppart + (size_t)(g * PM + c) * 96;
    s += slot[f];
    mx = fmaxf(mx, slot[32 + f]);
    mn = fminf(mn, slot[64 + f]);
  }
  float cnt = (float)(gstart[g + 1] - gstart[g]);
  float c = fmaxf(cnt, 1.0f);
  out[g * 128 + f] = s / c;
  out[g * 128 + 32 + f] = mx;
  out[g * 128 + 64 + f] = mn;
  out[g * 128 + 96 + f] = s;
}

// ---------------- host ----------------

extern "C" void kernel_launch(void* const* d_in, const int* in_sizes, int n_in,
                              void* d_out, int out_size, void* d_ws, size_t ws_size,
                              hipStream_t stream) {
  const float* x   = (const float*)d_in[0];
  const int*   ei  = (const int*)d_in[1];
  const int*   bat = (const int*)d_in[2];
  const float* W1  = (const float*)d_in[3];  const float* bc1 = (const float*)d_in[4];
  const float* W2  = (const float*)d_in[5];  const float* bc2 = (const float*)d_in[6];
  const float* W3  = (const float*)d_in[7];  const float* bc3 = (const float*)d_in[8];
  const float* W4  = (const float*)d_in[9];  const float* bc4 = (const float*)d_in[10];
  const float* g1  = (const float*)d_in[11]; const float* bt1 = (const float*)d_in[12];
  const float* g2  = (const float*)d_in[13]; const float* bt2 = (const float*)d_in[14];
  const float* g3  = (const float*)d_in[15]; const float* bt3 = (const float*)d_in[16];

  const int N = in_sizes[0] / 3;
  const int E = in_sizes[1] / 2;
  const int NG = out_size / 128;  // out: [NG][128] f32, out_size in ELEMENTS
  const int* src = ei;
  const int* dst = ei + E;
  const size_t Epad = (size_t)E + (size_t)(ROWPAD - 1) * N + 64;

  float* base = (float*)d_ws;
  size_t o = 0;
  auto alloc = [&](size_t n) -> float* {
    float* p = base + o;
    o += (n + 63) & ~(size_t)63;
    return p;
  };
  // zeroed region (contiguous from d_ws start):
  float* bnacc  = alloc(3 * 128);  // per-layer [sum64][sumsq64]
  size_t zero_elems = o;
  // uninitialized (fully overwritten before read):
  int*   gstart = (int*)alloc(NG + 1);
  float* ppart  = alloc((size_t)NG * PM * 96);
  int2*  erec  = (int2*)alloc(2 * Epad);
  float* dinv  = alloc(N);
  int*   hist  = (int*)alloc(N);
  int*   offs  = (int*)alloc(N + 1);
  int*   bsum  = (int*)alloc(256);
  int*   bbase = (int*)alloc(257);
  int*   bcnt  = (int*)alloc(MAXB);
  int*   bbase2 = (int*)alloc(MAXB + 1);
  int*   bcur  = (int*)alloc(MAXB);
  float* ab    = alloc(128);
  float* bias2 = alloc(192);          // L2[64] L3[64] L4[32]
  u16*   wt2   = (u16*)alloc(8192);   // bf16 [4][64][64]
  u16*   wt3   = (u16*)alloc(8192);
  u16*   wt4   = (u16*)alloc(4096);   // bf16 [4][32][64]
  float* t1f   = alloc(3 * (size_t)N);
  float* t2f   = alloc(3 * (size_t)N);
  float* t3f   = alloc(3 * (size_t)N);
  u16*   T0    = (u16*)alloc((size_t)N * 32);  // bf16 [N][64]
  u16*   T1    = (u16*)alloc((size_t)N * 32);
  u16*   T2    = (u16*)alloc((size_t)N * 32);
  u16*   T3    = (u16*)alloc((size_t)N * 32);
  float* C32   = alloc((size_t)N * 32);

  hipMemsetAsync(d_ws, 0, zero_elems * sizeof(float), stream);

  const int NB = (N + 255) / 256;
  const int SB = (N + SC_CHUNK - 1) / SC_CHUNK;
  const int S  = (N + HSEG - 1) / HSEG;
  const int SP = S * HSEG;
  const int NBK = (N + 255) >> 8;
  unsigned* partial = (unsigned*)T0;  // alias
  int2* ebuck = (int2*)T2;            // alias

  k_wprep<<<64, 256, 0, stream>>>(W2, W3, W4, wt2, wt3, wt4);
  k_gbound<<<1, 128, 0, stream>>>(bat, gstart, N, NG);
  k_histseg<<<dim3(S, HC, 2), 256, 0, stream>>>(src, dst, partial, E, SP);
  k_histred<<<NB, 256, 0, stream>>>((const u8*)partial, dinv, hist, N, SP);
  k_scan1<<<SB, 256, 0, stream>>>(hist, bsum, N);
  k_scan2<<<1, 256, 0, stream>>>(bsum, bbase, SB);
  k_scan3<<<SB, 256, 0, stream>>>(hist, bbase, offs, N, SB);
  k_bcnt<<<NBK, 256, 0, stream>>>(hist, bcnt, N);
  k_bscan<<<1, 256, 0, stream>>>(bcnt, bbase2, bcur, NBK);
  k_part<<<512, 256, 0, stream>>>(src, dst, bcur, ebuck, E);
  k_place<<<NBK, 256, 0, stream>>>(ebuck, bbase2, offs, dinv, erec, N);

  const int PB64 = (N * 64 + 255) / 256;
  const int TB = (N + 63) / 64;
  const int NCB = TB < 512 ? TB : 512;  // combine grid: 2 blocks/CU, grid-stride over tiles
  const v4i* erec4 = (const v4i*)erec;

  // ---- layer 1: Fin=3 -> 64 (f32 props, merged combine w/ fused lrelu+BN stats) ----
  k_prop3<<<NB, 256, 0, stream>>>(x, nullptr, t1f, offs, erec4, N, 0);
  k_prop3<<<NB, 256, 0, stream>>>(t1f, x, t2f, offs, erec4, N, 1);
  k_prop3<<<NB, 256, 0, stream>>>(t2f, t1f, t3f, offs, erec4, N, 1);
  k_combine1<<<512, 256, 0, stream>>>(T0, x, t1f, t2f, t3f, W1, bc1, bnacc, N);
  k_bnfinal3<<<1, 256, 0, stream>>>(bnacc, g1, bt1, W2, bc2, ab, bias2, 1.0f / N, 64);

  // ---- layer 2 ----
  k_prop64b<1, 0, 0><<<PB64, 256, 0, stream>>>(T0, ab, nullptr, nullptr, T1, offs, erec4, N);
  k_prop64b<0, 1, 1><<<PB64, 256, 0, stream>>>(T1, nullptr, T0, ab, T2, offs, erec4, N);
  k_prop64b<0, 1, 0><<<PB64, 256, 0, stream>>>(T2, nullptr, T1, nullptr, T3, offs, erec4, N);
  k_combine_m<64, true, true><<<NCB, 256, 0, stream>>>(T0, T0, T1, T2, T3, wt2, ab, bias2,
                                                       bnacc + 128, N, TB);
  k_bnfinal3<<<1, 256, 0, stream>>>(bnacc + 128, g2, bt2, W3, bc3, ab, bias2 + 64, 1.0f / N, 64);

  // ---- layer 3 ----
  k_prop64b<1, 0, 0><<<PB64, 256, 0, stream>>>(T0, ab, nullptr, nullptr, T1, offs, erec4, N);
  k_prop64b<0, 1, 1><<<PB64, 256, 0, stream>>>(T1, nullptr, T0, ab, T2, offs, erec4, N);
  k_prop64b<0, 1, 0><<<PB64, 256, 0, stream>>>(T2, nullptr, T1, nullptr, T3, offs, erec4, N);
  k_combine_m<64, true, true><<<NCB, 256, 0, stream>>>(T0, T0, T1, T2, T3, wt3, ab, bias2 + 64,
                                                       bnacc + 256, N, TB);
  k_bnfinal3<<<1, 256, 0, stream>>>(bnacc + 256, g3, bt3, W4, bc4, ab, bias2 + 128, 1.0f / N, 32);

  // ---- layer 4: 64 -> 32 (f32 out C32) ----
  k_prop64b<1, 0, 0><<<PB64, 256, 0, stream>>>(T0, ab, nullptr, nullptr, T1, offs, erec4, N);
  k_prop64b<0, 1, 1><<<PB64, 256, 0, stream>>>(T1, nullptr, T0, ab, T2, offs, erec4, N);
  k_prop64b<0, 1, 0><<<PB64, 256, 0, stream>>>(T2, nullptr, T1, nullptr, T3, offs, erec4, N);
  k_combine_m<32, false, false><<<NCB, 256, 0, stream>>>(C32, T0, T1, T2, T3, wt4, ab, bias2 + 128,
                                                         nullptr, N, TB);

  // ---- pool (L2-normalize fused, atomic-free) ----
  k_pool3<<<NG * PM, 256, 0, stream>>>(C32, gstart, ppart);
  k_poolfin2<<<NG, 32, 0, stream>>>(ppart, gstart, (float*)d_out);
}